// Round 1
// baseline (210.823 us; speedup 1.0000x reference)
//
#include <hip/hip_runtime.h>
#include <hip/hip_bf16.h>
#include <cstdint>
#include <cstddef>
#include <type_traits>

// FocalAttention: B=4 T=2048 D=1024 H=16 hd=64 RADIUS=4 (banded, 9-wide window)
// fp32 in/out. cvt(fp32->bf16) -> gemm_qkv (8-phase 256x256 template, qkv in
// [b,h,s,t,d] layout) -> banded attn (4 threads/query) -> gemm_proj 128x128 (fp32 out).
// r7 lesson: never split the GEMM grid below ~4 blocks/CU for the 128x128 kernel.
// r8 (this round): gemm_qkv ported to the 256^2 8-phase counted-vmcnt template
// (T2 swizzle + T3/T4 counted vmcnt(8) + T5 setprio). Schedule invariants:
//   - tile t+2 shares the LDS buffer being read for tile t (parity), so
//     B(t+2) stages issue in P3 (B region last read P2), A(t+2) in P4 (A last read P3).
//   - per-wave ledger at P4 wait: 8 loads in flight from t+1 + 8 issued this tile
//     => s_waitcnt vmcnt(8) drains exactly tile t+1, keeps t+2 in flight.
//   - tail: vmcnt(0) at t=NT-2, nothing at t=NT-1.

typedef __hip_bfloat16 bf16;
typedef __attribute__((ext_vector_type(8))) short bf16x8;   // A/B frag: 8 bf16 = 4 VGPRs
typedef __attribute__((ext_vector_type(4))) float f32x4;    // C/D frag
typedef __attribute__((ext_vector_type(8))) unsigned short u16x8;

#define BATCH  4
#define SEQ    2048
#define DIM    1024
#define NHEAD  16
#define HDIM   64
#define RADIUS 4
#define ROWS   (BATCH * SEQ)          // 8192
#define KDIM   1024
#define NT     (KDIM / 64)            // 16 K-tiles
#define HSLICE (SEQ * HDIM)           // elems per (b,h,s) slice

__device__ __forceinline__ void async_copy16(const void* gptr, void* lptr) {
    __builtin_amdgcn_global_load_lds(
        (const __attribute__((address_space(1))) unsigned int*)(uintptr_t)gptr,
        (__attribute__((address_space(3))) unsigned int*)(uint32_t)(uintptr_t)lptr,
        16, 0, 0);
}

// Fused fp32 -> bf16 convert for all three tensors, 8 elems/thread.
__global__ __launch_bounds__(256)
void cvt_all(const float* __restrict__ s1, bf16* __restrict__ d1, int n1,
             const float* __restrict__ s2, bf16* __restrict__ d2, int n2,
             const float* __restrict__ s3, bf16* __restrict__ d3, int n3) {
    int i = blockIdx.x * blockDim.x + threadIdx.x;
    const float* src; bf16* dst;
    if (i < n1)              { src = s1; dst = d1; }
    else if (i < n1 + n2)    { i -= n1; src = s2; dst = d2; }
    else if (i < n1+n2+n3)   { i -= n1 + n2; src = s3; dst = d3; }
    else return;
    const float4 a = ((const float4*)src)[2 * i];
    const float4 b = ((const float4*)src)[2 * i + 1];
    union { u16x8 v; __hip_bfloat16 h[8]; } o;
    o.h[0] = __float2bfloat16(a.x); o.h[1] = __float2bfloat16(a.y);
    o.h[2] = __float2bfloat16(a.z); o.h[3] = __float2bfloat16(a.w);
    o.h[4] = __float2bfloat16(b.x); o.h[5] = __float2bfloat16(b.y);
    o.h[6] = __float2bfloat16(b.z); o.h[7] = __float2bfloat16(b.w);
    ((u16x8*)dst)[i] = o.v;
}

// ---------------------------------------------------------------------------
// gemm_qkv: 8-phase 256x256 template. C[row][col] = A[row,:] . B[col,:] + bias,
// scattered to qkv [b,h,s,t,d] layout in bf16.
// ---------------------------------------------------------------------------

// phase barrier: IR memory fence + machine sched fence + hw barrier (no vmcnt drain)
#define PHB() do {                                  \
    asm volatile("" ::: "memory");                  \
    __builtin_amdgcn_sched_barrier(0);              \
    __builtin_amdgcn_s_barrier();                   \
    __builtin_amdgcn_sched_barrier(0);              \
    asm volatile("" ::: "memory");                  \
} while (0)

// stage one 128-row half-tile (2 x global_load_lds_dwordx4 per thread).
// XOR swizzle lives in the SOURCE address (kg); LDS dest stays linear
// (global_load_lds requires wave-uniform base + lane*16).
#define STAGE_A(buf_, half_, kt_) do {                                          \
    _Pragma("unroll")                                                           \
    for (int i_ = 0; i_ < 2; ++i_) {                                            \
        const int c_   = i_ * 512 + tid;                                        \
        const int row_ = (half_) * 128 + (c_ >> 3);                             \
        const int kg_  = (c_ & 7) ^ (row_ & 7);                                 \
        async_copy16(A + (size_t)(tileM + row_) * KDIM + (kt_) + kg_ * 8,       \
                     (char*)As[buf_] + ((half_) * 1024 + c_) * 16);             \
    } } while (0)

#define STAGE_B(buf_, half_, kt_) do {                                          \
    _Pragma("unroll")                                                           \
    for (int i_ = 0; i_ < 2; ++i_) {                                            \
        const int c_   = i_ * 512 + tid;                                        \
        const int row_ = (half_) * 128 + (c_ >> 3);                             \
        const int kg_  = (c_ & 7) ^ (row_ & 7);                                 \
        async_copy16(B + (size_t)(tileN + row_) * KDIM + (kt_) + kg_ * 8,       \
                     (char*)Bs[buf_] + ((half_) * 1024 + c_) * 16);             \
    } } while (0)

// LDS -> register fragments (swizzled read side; row&7 == l16&7)
#define LDA_Q(mh_) do {                                                         \
    _Pragma("unroll")                                                           \
    for (int ks_ = 0; ks_ < 2; ++ks_)                                           \
    _Pragma("unroll")                                                           \
    for (int mt_ = 0; mt_ < 4; ++mt_)                                           \
        aF[ks_][mt_] = *(const bf16x8*)(as_ +                                   \
            (size_t)(wm * 128 + (mh_) * 64 + mt_ * 16 + l16) * 64 +             \
            ((((ks_ << 2) | quad) ^ hh) << 3));                                 \
} while (0)

#define LDB_Q(BF_, nh_) do {                                                    \
    _Pragma("unroll")                                                           \
    for (int ks_ = 0; ks_ < 2; ++ks_)                                           \
    _Pragma("unroll")                                                           \
    for (int nt_ = 0; nt_ < 2; ++nt_)                                           \
        BF_[ks_][nt_] = *(const bf16x8*)(bs_ +                                  \
            (size_t)(wn * 64 + (nh_) * 32 + nt_ * 16 + l16) * 64 +              \
            ((((ks_ << 2) | quad) ^ hh) << 3));                                 \
} while (0)

// one C-quadrant over the full K=64 tile: 4m x 2n x 2k = 16 MFMA.
// ks outermost -> dependency distance 8 between writes to the same acc.
#define MFMA_Q(mh_, nh_, BF_) do {                                              \
    _Pragma("unroll")                                                           \
    for (int ks_ = 0; ks_ < 2; ++ks_)                                           \
    _Pragma("unroll")                                                           \
    for (int mt_ = 0; mt_ < 4; ++mt_)                                           \
    _Pragma("unroll")                                                           \
    for (int nt_ = 0; nt_ < 2; ++nt_)                                           \
        acc[(mh_) * 4 + mt_][(nh_) * 2 + nt_] =                                 \
            __builtin_amdgcn_mfma_f32_16x16x32_bf16(                            \
                aF[ks_][mt_], BF_[ks_][nt_],                                    \
                acc[(mh_) * 4 + mt_][(nh_) * 2 + nt_], 0, 0, 0);                \
} while (0)

__global__ __launch_bounds__(512, 1)
void gemm_qkv_8p(const bf16* __restrict__ A, const bf16* __restrict__ B,
                 const float* __restrict__ bias, bf16* __restrict__ C) {
    __shared__ bf16 As[2][256 * 64];   // 64 KB
    __shared__ bf16 Bs[2][256 * 64];   // 64 KB  (128 KB total -> 1 block/CU)

    const int tid  = threadIdx.x;
    const int l16  = tid & 15;
    const int quad = (tid >> 4) & 3;
    const int wave = tid >> 6;          // 0..7
    const int wm   = wave >> 2;         // 0..1  (M split)
    const int wn   = wave & 3;          // 0..3  (N split)
    const int hh   = l16 & 7;

    // XCD-aware swizzle: grid = 384 = 32 Mtiles x 12 Ntiles; 384 % 8 == 0 -> bijective.
    int bid = (int)blockIdx.x;
    bid = (bid & 7) * 48 + (bid >> 3);
    const int tileM = (bid / 12) * 256;
    const int tileN = (bid % 12) * 256;

    f32x4  acc[8][4] = {};
    bf16x8 aF[2][4], bF0[2][2], bF1[2][2];

    // prologue: stage tiles 0 and 1 fully; drain tile 0 (16 issued, keep 8 in flight)
    STAGE_A(0, 0, 0);  STAGE_B(0, 0, 0);  STAGE_A(0, 1, 0);  STAGE_B(0, 1, 0);
    STAGE_A(1, 0, 64); STAGE_B(1, 0, 64); STAGE_A(1, 1, 64); STAGE_B(1, 1, 64);
    asm volatile("s_waitcnt vmcnt(8)" ::: "memory");
    PHB();

    #pragma unroll 1
    for (int t = 0; t < NT; ++t) {
        const int buf = t & 1;
        const bf16* __restrict__ as_ = &As[buf][0];
        const bf16* __restrict__ bs_ = &Bs[buf][0];
        const int  kt2 = (t + 2) * 64;
        const bool pf  = (t + 2 < NT);

        // ---- P1: quadrant (m0,n0); 12 ds_read_b128 ----
        LDA_Q(0);
        LDB_Q(bF0, 0);
        PHB();
        __builtin_amdgcn_s_setprio(1);
        MFMA_Q(0, 0, bF0);
        __builtin_amdgcn_s_setprio(0);
        PHB();

        // ---- P2: quadrant (m0,n1); 4 ds_read_b128 ----
        LDB_Q(bF1, 1);
        PHB();
        __builtin_amdgcn_s_setprio(1);
        MFMA_Q(0, 1, bF1);
        __builtin_amdgcn_s_setprio(0);
        PHB();

        // ---- P3: quadrant (m1,n1); 8 ds_read_b128; stage B(t+2) (B reads done @P2) ----
        LDA_Q(1);
        if (pf) { STAGE_B(buf, 0, kt2); STAGE_B(buf, 1, kt2); }
        PHB();
        __builtin_amdgcn_s_setprio(1);
        MFMA_Q(1, 1, bF1);
        __builtin_amdgcn_s_setprio(0);
        PHB();

        // ---- P4: quadrant (m1,n0); stage A(t+2) (A reads done @P3); counted drain ----
        if (pf) { STAGE_A(buf, 0, kt2); STAGE_A(buf, 1, kt2); }
        PHB();
        __builtin_amdgcn_s_setprio(1);
        MFMA_Q(1, 0, bF0);
        __builtin_amdgcn_s_setprio(0);
        if (pf)                 asm volatile("s_waitcnt vmcnt(8)" ::: "memory");
        else if (t + 1 < NT)    asm volatile("s_waitcnt vmcnt(0)" ::: "memory");
        PHB();
    }

    // epilogue: C/D layout col = lane&15, row = quad*4 + reg  [m89/m91-verified]
    #pragma unroll
    for (int an = 0; an < 4; ++an) {
        const int scol = tileN + wn * 64 + an * 16;
        const int cl   = scol + l16;
        const float bv = bias[cl];
        const int s = cl >> 10;
        const int h = (cl >> 6) & (NHEAD - 1);
        const int d = cl & 63;
        #pragma unroll
        for (int am = 0; am < 8; ++am) {
            #pragma unroll
            for (int r = 0; r < 4; ++r) {
                const int rowg = tileM + wm * 128 + am * 16 + quad * 4 + r;
                const int b  = rowg >> 11;
                const int tt = rowg & (SEQ - 1);
                C[(size_t)((b * NHEAD + h) * 3 + s) * HSLICE
                  + (size_t)tt * HDIM + d] =
                    __float2bfloat16(acc[am][an][r] + bv);
            }
        }
    }
}

// ---------------------------------------------------------------------------
// gemm_proj: unchanged 128x128 single-buffer kernel (512 blocks = 2/CU).
// ---------------------------------------------------------------------------
template <int NMAT, typename OutT>
__device__ __forceinline__
void gemm_body(const bf16* __restrict__ A, const bf16* __restrict__ B,
               const float* __restrict__ bias, OutT* __restrict__ C) {
    __shared__ bf16 As[128 * 64];   // 16 KB
    __shared__ bf16 Bs[128 * 64];   // 16 KB

    const int tid  = threadIdx.x;
    const int lane = tid & 63;
    const int wave = tid >> 6;
    const int quad = lane >> 4;
    const int l16  = lane & 15;

    const int tileM = blockIdx.y * 128;
    const int tileN = blockIdx.x * 128;
    const int wm = (wave >> 1) * 64;
    const int wn = (wave & 1) * 64;

    f32x4 acc[4][4] = {};

    for (int kt = 0; kt < KDIM; kt += 64) {
        #pragma unroll
        for (int i = 0; i < 4; ++i) {
            const int c   = i * 256 + tid;
            const int row = c >> 3;
            const int kg  = (c & 7) ^ (row & 7);   // XOR swizzle
            async_copy16(A + (size_t)(tileM + row) * KDIM + kt + kg * 8,
                         (char*)As + c * 16);
            async_copy16(B + (size_t)(tileN + row) * KDIM + kt + kg * 8,
                         (char*)Bs + c * 16);
        }
        __syncthreads();

        #pragma unroll
        for (int ks = 0; ks < 2; ++ks) {
            const int kq = ks * 4 + quad;
            const int so = (kq ^ (l16 & 7)) * 8;
            bf16x8 aF[4], bF[4];
            #pragma unroll
            for (int mt = 0; mt < 4; ++mt)
                aF[mt] = *(const bf16x8*)(As + (wm + mt * 16 + l16) * 64 + so);
            #pragma unroll
            for (int nt = 0; nt < 4; ++nt)
                bF[nt] = *(const bf16x8*)(Bs + (wn + nt * 16 + l16) * 64 + so);

            #pragma unroll
            for (int mt = 0; mt < 4; ++mt)
                #pragma unroll
                for (int nt = 0; nt < 4; ++nt)
                    acc[mt][nt] = __builtin_amdgcn_mfma_f32_16x16x32_bf16(
                        aF[mt], bF[nt], acc[mt][nt], 0, 0, 0);
        }
        __syncthreads();
    }

    #pragma unroll
    for (int nt = 0; nt < 4; ++nt) {
        const int scol = tileN + wn + nt * 16;
        const float bv = bias[scol + l16];
        #pragma unroll
        for (int mt = 0; mt < 4; ++mt) {
            #pragma unroll
            for (int r = 0; r < 4; ++r) {
                const int rowg = tileM + wm + mt * 16 + quad * 4 + r;
                const float v = acc[mt][nt][r] + bv;
                C[(size_t)rowg * NMAT + scol + l16] = v;
            }
        }
    }
}

__global__ __launch_bounds__(256)
void gemm_proj(const bf16* __restrict__ A, const bf16* __restrict__ B,
               const float* __restrict__ bias, float* __restrict__ C) {
    gemm_body<1024, float>(A, B, bias, C);
}

// ---- 8 bf16 (as uint4) -> 8 floats
__device__ __forceinline__ void bf8_to_f32(const uint4 u, float* f) {
    union { uint32_t u; float f; } c;
    c.u = u.x << 16;         f[0] = c.f;
    c.u = u.x & 0xffff0000u; f[1] = c.f;
    c.u = u.y << 16;         f[2] = c.f;
    c.u = u.y & 0xffff0000u; f[3] = c.f;
    c.u = u.z << 16;         f[4] = c.f;
    c.u = u.z & 0xffff0000u; f[5] = c.f;
    c.u = u.w << 16;         f[6] = c.f;
    c.u = u.w & 0xffff0000u; f[7] = c.f;
}

// Banded attention v4 over [b,h,s,t,d] qkv: 4 threads/query (16 dims each).
__global__ __launch_bounds__(256)
void attn_banded4(const bf16* __restrict__ qkv, bf16* __restrict__ aout) {
    const int tid = threadIdx.x;
    const int qi  = tid >> 2;          // 0..63
    const int ch  = tid & 3;           // 16-dim chunk
    const int t   = blockIdx.x * 64 + qi;
    const int h   = blockIdx.y;
    const int b   = blockIdx.z;

    const size_t bh3 = (size_t)(b * NHEAD + h) * 3;
    const bf16* qb = qkv + (bh3 + 0) * HSLICE + (size_t)t * HDIM + ch * 16;
    const bf16* kb = qkv + (bh3 + 1) * HSLICE + ch * 16;
    const bf16* vb = qkv + (bh3 + 2) * HSLICE + ch * 16;
    const float scale = 0.125f;        // hd^-0.5

    float q16[16];
    {
        const uint4* qp = (const uint4*)qb;
        uint4 u0 = qp[0], u1 = qp[1];
        bf8_to_f32(u0, q16); bf8_to_f32(u1, q16 + 8);
    }

    float sc[2 * RADIUS + 1];
    #pragma unroll
    for (int j = 0; j < 2 * RADIUS + 1; ++j) {
        const int k = t - RADIUS + j;
        const bool valid = (k >= 0) && (k < SEQ);
        const int kc = valid ? k : t;
        const uint4* kp = (const uint4*)(kb + (size_t)kc * HDIM);
        float kf[16];
        uint4 u0 = kp[0], u1 = kp[1];
        bf8_to_f32(u0, kf); bf8_to_f32(u1, kf + 8);
        float p = 0.f;
        #pragma unroll
        for (int e = 0; e < 16; ++e) p = fmaf(q16[e], kf[e], p);
        p += __shfl_xor(p, 1, 64);     // merge 4 chunks
        p += __shfl_xor(p, 2, 64);
        sc[j] = valid ? p * scale : -1e30f;
    }

    float mx = sc[0];
    #pragma unroll
    for (int j = 1; j < 2 * RADIUS + 1; ++j) mx = fmaxf(mx, sc[j]);
    float sum = 0.f;
    #pragma unroll
    for (int j = 0; j < 2 * RADIUS + 1; ++j) { sc[j] = __expf(sc[j] - mx); sum += sc[j]; }
    const float inv = 1.0f / sum;

    float o16[16];
    #pragma unroll
    for (int e = 0; e < 16; ++e) o16[e] = 0.f;
    #pragma unroll
    for (int j = 0; j < 2 * RADIUS + 1; ++j) {
        const int k = t - RADIUS + j;
        const int kc = (k >= 0 && k < SEQ) ? k : t;   // weight ~0 when clamped
        const uint4* vp = (const uint4*)(vb + (size_t)kc * HDIM);
        float vf[16];
        uint4 u0 = vp[0], u1 = vp[1];
        bf8_to_f32(u0, vf); bf8_to_f32(u1, vf + 8);
        const float w = sc[j];
        #pragma unroll
        for (int e = 0; e < 16; ++e) o16[e] = fmaf(w, vf[e], o16[e]);
    }

    bf16* op = aout + ((size_t)b * SEQ + t) * DIM + h * HDIM + ch * 16;
    #pragma unroll
    for (int c2 = 0; c2 < 2; ++c2) {
        union { u16x8 v; __hip_bfloat16 hh[8]; } o;
        #pragma unroll
        for (int e = 0; e < 8; ++e) o.hh[e] = __float2bfloat16(o16[c2 * 8 + e] * inv);
        ((u16x8*)op)[c2] = o.v;
    }
}

extern "C" void kernel_launch(void* const* d_in, const int* in_sizes, int n_in,
                              void* d_out, int out_size, void* d_ws, size_t ws_size,
                              hipStream_t stream) {
    const float* x      = (const float*)d_in[0];
    const float* w_qkv  = (const float*)d_in[1];
    const float* b_qkv  = (const float*)d_in[2];
    const float* w_proj = (const float*)d_in[3];
    const float* b_proj = (const float*)d_in[4];
    float* out = (float*)d_out;

    bf16* xb     = (bf16*)d_ws;
    bf16* wqkvb  = xb + (size_t)ROWS * DIM;
    bf16* wprojb = wqkvb + (size_t)3072 * 1024;
    bf16* qkvb   = wprojb + (size_t)1024 * 1024;   // [b,h,s,t,d], 48 MiB
    bf16* attnb  = qkvb + (size_t)ROWS * 3072;

    const int n1 = ROWS * DIM / 8, n2 = 3072 * 1024 / 8, n3 = 1024 * 1024 / 8;
    cvt_all<<<(n1 + n2 + n3 + 255) / 256, 256, 0, stream>>>(x, xb, n1, w_qkv, wqkvb, n2,
                                                            w_proj, wprojb, n3);

    // GEMM1: 8-phase 256x256 template, 384 blocks (32 Mtiles x 12 Ntiles)
    gemm_qkv_8p<<<dim3(384), 512, 0, stream>>>(xb, wqkvb, b_qkv, qkvb);

    // attn v4: 4 threads/query, 32 waves/CU
    attn_banded4<<<dim3(SEQ / 64, NHEAD, BATCH), 256, 0, stream>>>(qkvb, attnb);

    // GEMM2: 128x128 tiles, 512 blocks
    gemm_proj<<<dim3(1024 / 128, ROWS / 128), 256, 0, stream>>>(attnb, wprojb, b_proj, out);
}

// Round 2
// 202.638 us; speedup vs baseline: 1.0404x; 1.0404x over previous
//
#include <hip/hip_runtime.h>
#include <hip/hip_bf16.h>
#include <cstdint>
#include <cstddef>
#include <type_traits>

// FocalAttention: B=4 T=2048 D=1024 H=16 hd=64 RADIUS=4 (banded, 9-wide window)
// fp32 in/out. cvt(fp32->bf16) -> gemm_qkv (8-phase 256x256) -> banded attn
// (4 threads/query) -> gemm_proj 128x128 (fp32 out).
// r7 lesson: never split the 128x128 GEMM grid below ~4 blocks/CU.
// r8 lesson (POST-MORTEM): wrapping every s_barrier in sched_barrier(0)+memory
// fences reproduced the m141 regression (0.55x) — 16 scheduler pins per K-tile
// serialized the ds_read/MFMA interleave. This round: bare s_barrier + bare
// lgkmcnt(0) per phase (exact m201 template form); counted vmcnt keeps "memory".
// Correctness without fences: ds_reads are anchored by MFMA uses before the
// region-end barrier; side-effecting ops (s_barrier / global_load_lds / volatile
// asm) don't reorder among themselves; vmcnt asm keeps "memory" so next-phase
// ds_reads can't hoist above the drain.

typedef __hip_bfloat16 bf16;
typedef __attribute__((ext_vector_type(8))) short bf16x8;   // A/B frag: 8 bf16 = 4 VGPRs
typedef __attribute__((ext_vector_type(4))) float f32x4;    // C/D frag
typedef __attribute__((ext_vector_type(8))) unsigned short u16x8;

#define BATCH  4
#define SEQ    2048
#define DIM    1024
#define NHEAD  16
#define HDIM   64
#define RADIUS 4
#define ROWS   (BATCH * SEQ)          // 8192
#define KDIM   1024
#define NT     (KDIM / 64)            // 16 K-tiles
#define HSLICE (SEQ * HDIM)           // elems per (b,h,s) slice

__device__ __forceinline__ void async_copy16(const void* gptr, void* lptr) {
    __builtin_amdgcn_global_load_lds(
        (const __attribute__((address_space(1))) unsigned int*)(uintptr_t)gptr,
        (__attribute__((address_space(3))) unsigned int*)(uint32_t)(uintptr_t)lptr,
        16, 0, 0);
}

// Fused fp32 -> bf16 convert for all three tensors, 8 elems/thread.
__global__ __launch_bounds__(256)
void cvt_all(const float* __restrict__ s1, bf16* __restrict__ d1, int n1,
             const float* __restrict__ s2, bf16* __restrict__ d2, int n2,
             const float* __restrict__ s3, bf16* __restrict__ d3, int n3) {
    int i = blockIdx.x * blockDim.x + threadIdx.x;
    const float* src; bf16* dst;
    if (i < n1)              { src = s1; dst = d1; }
    else if (i < n1 + n2)    { i -= n1; src = s2; dst = d2; }
    else if (i < n1+n2+n3)   { i -= n1 + n2; src = s3; dst = d3; }
    else return;
    const float4 a = ((const float4*)src)[2 * i];
    const float4 b = ((const float4*)src)[2 * i + 1];
    union { u16x8 v; __hip_bfloat16 h[8]; } o;
    o.h[0] = __float2bfloat16(a.x); o.h[1] = __float2bfloat16(a.y);
    o.h[2] = __float2bfloat16(a.z); o.h[3] = __float2bfloat16(a.w);
    o.h[4] = __float2bfloat16(b.x); o.h[5] = __float2bfloat16(b.y);
    o.h[6] = __float2bfloat16(b.z); o.h[7] = __float2bfloat16(b.w);
    ((u16x8*)dst)[i] = o.v;
}

// ---------------------------------------------------------------------------
// gemm_qkv: 8-phase 256x256 template. C[row][col] = A[row,:] . B[col,:] + bias,
// scattered to qkv [b,h,s,t,d] layout in bf16.
// Schedule invariants (unchanged from r8, re-verified):
//   - tile t+2 shares the LDS buffer read for tile t; B(t+2) stages in P3
//     (B region last read P2), A(t+2) in P4 (A last read P3).
//   - per-wave ledger at P4 wait: 8 in flight from t+1 + 8 issued this tile
//     => vmcnt(8) drains exactly tile t+1, keeps t+2 in flight.
//   - tail: vmcnt(0) at t=NT-2, nothing at t=NT-1.
// ---------------------------------------------------------------------------

#define BAR()        __builtin_amdgcn_s_barrier()
#define WAIT_LGKM0() asm volatile("s_waitcnt lgkmcnt(0)")

#define STAGE_A(buf_, half_, kt_) do {                                          \
    _Pragma("unroll")                                                           \
    for (int i_ = 0; i_ < 2; ++i_) {                                            \
        const int c_   = i_ * 512 + tid;                                        \
        const int row_ = (half_) * 128 + (c_ >> 3);                             \
        const int kg_  = (c_ & 7) ^ (row_ & 7);                                 \
        async_copy16(A + (size_t)(tileM + row_) * KDIM + (kt_) + kg_ * 8,       \
                     (char*)As[buf_] + ((half_) * 1024 + c_) * 16);             \
    } } while (0)

#define STAGE_B(buf_, half_, kt_) do {                                          \
    _Pragma("unroll")                                                           \
    for (int i_ = 0; i_ < 2; ++i_) {                                            \
        const int c_   = i_ * 512 + tid;                                        \
        const int row_ = (half_) * 128 + (c_ >> 3);                             \
        const int kg_  = (c_ & 7) ^ (row_ & 7);                                 \
        async_copy16(B + (size_t)(tileN + row_) * KDIM + (kt_) + kg_ * 8,       \
                     (char*)Bs[buf_] + ((half_) * 1024 + c_) * 16);             \
    } } while (0)

// LDS -> register fragments (swizzled read side; row&7 == l16&7)
#define LDA_Q(mh_) do {                                                         \
    _Pragma("unroll")                                                           \
    for (int ks_ = 0; ks_ < 2; ++ks_)                                           \
    _Pragma("unroll")                                                           \
    for (int mt_ = 0; mt_ < 4; ++mt_)                                           \
        aF[ks_][mt_] = *(const bf16x8*)(as_ +                                   \
            (size_t)(wm * 128 + (mh_) * 64 + mt_ * 16 + l16) * 64 +             \
            ((((ks_ << 2) | quad) ^ hh) << 3));                                 \
} while (0)

#define LDB_Q(BF_, nh_) do {                                                    \
    _Pragma("unroll")                                                           \
    for (int ks_ = 0; ks_ < 2; ++ks_)                                           \
    _Pragma("unroll")                                                           \
    for (int nt_ = 0; nt_ < 2; ++nt_)                                           \
        BF_[ks_][nt_] = *(const bf16x8*)(bs_ +                                  \
            (size_t)(wn * 64 + (nh_) * 32 + nt_ * 16 + l16) * 64 +              \
            ((((ks_ << 2) | quad) ^ hh) << 3));                                 \
} while (0)

// one C-quadrant over the full K=64 tile: 4m x 2n x 2k = 16 MFMA.
#define MFMA_Q(mh_, nh_, BF_) do {                                              \
    _Pragma("unroll")                                                           \
    for (int ks_ = 0; ks_ < 2; ++ks_)                                           \
    _Pragma("unroll")                                                           \
    for (int mt_ = 0; mt_ < 4; ++mt_)                                           \
    _Pragma("unroll")                                                           \
    for (int nt_ = 0; nt_ < 2; ++nt_)                                           \
        acc[(mh_) * 4 + mt_][(nh_) * 2 + nt_] =                                 \
            __builtin_amdgcn_mfma_f32_16x16x32_bf16(                            \
                aF[ks_][mt_], BF_[ks_][nt_],                                    \
                acc[(mh_) * 4 + mt_][(nh_) * 2 + nt_], 0, 0, 0);                \
} while (0)

__global__ __launch_bounds__(512, 1)
void gemm_qkv_8p(const bf16* __restrict__ A, const bf16* __restrict__ B,
                 const float* __restrict__ bias, bf16* __restrict__ C) {
    __shared__ bf16 As[2][256 * 64];   // 64 KB
    __shared__ bf16 Bs[2][256 * 64];   // 64 KB  (128 KB total -> 1 block/CU)

    const int tid  = threadIdx.x;
    const int l16  = tid & 15;
    const int quad = (tid >> 4) & 3;
    const int wave = tid >> 6;          // 0..7
    const int wm   = wave >> 2;         // 0..1  (M split)
    const int wn   = wave & 3;          // 0..3  (N split)
    const int hh   = l16 & 7;

    // XCD-aware swizzle: grid = 384 = 32 Mtiles x 12 Ntiles; 384 % 8 == 0 -> bijective.
    int bid = (int)blockIdx.x;
    bid = (bid & 7) * 48 + (bid >> 3);
    const int tileM = (bid / 12) * 256;
    const int tileN = (bid % 12) * 256;

    f32x4  acc[8][4] = {};
    bf16x8 aF[2][4], bF0[2][2], bF1[2][2];

    // prologue: stage tiles 0 and 1 fully; drain tile 0 (16 issued, keep 8 in flight)
    STAGE_A(0, 0, 0);  STAGE_B(0, 0, 0);  STAGE_A(0, 1, 0);  STAGE_B(0, 1, 0);
    STAGE_A(1, 0, 64); STAGE_B(1, 0, 64); STAGE_A(1, 1, 64); STAGE_B(1, 1, 64);
    asm volatile("s_waitcnt vmcnt(8)" ::: "memory");
    BAR();

    #pragma unroll 1
    for (int t = 0; t < NT; ++t) {
        const int buf = t & 1;
        const bf16* __restrict__ as_ = &As[buf][0];
        const bf16* __restrict__ bs_ = &Bs[buf][0];
        const int  kt2 = (t + 2) * 64;
        const bool pf  = (t + 2 < NT);

        // ---- P1: quadrant (m0,n0); 12 ds_read_b128 ----
        LDA_Q(0);
        LDB_Q(bF0, 0);
        asm volatile("s_waitcnt lgkmcnt(8)");   // template's optional hint (12 issued)
        BAR();
        WAIT_LGKM0();
        __builtin_amdgcn_s_setprio(1);
        MFMA_Q(0, 0, bF0);
        __builtin_amdgcn_s_setprio(0);
        BAR();

        // ---- P2: quadrant (m0,n1); 4 ds_read_b128 ----
        LDB_Q(bF1, 1);
        BAR();
        WAIT_LGKM0();
        __builtin_amdgcn_s_setprio(1);
        MFMA_Q(0, 1, bF1);
        __builtin_amdgcn_s_setprio(0);
        BAR();

        // ---- P3: quadrant (m1,n1); 8 ds_read_b128; stage B(t+2) (B reads done @P2) ----
        LDA_Q(1);
        if (pf) { STAGE_B(buf, 0, kt2); STAGE_B(buf, 1, kt2); }
        BAR();
        WAIT_LGKM0();
        __builtin_amdgcn_s_setprio(1);
        MFMA_Q(1, 1, bF1);
        __builtin_amdgcn_s_setprio(0);
        BAR();

        // ---- P4: quadrant (m1,n0); stage A(t+2) (A reads done @P3); counted drain ----
        if (pf) { STAGE_A(buf, 0, kt2); STAGE_A(buf, 1, kt2); }
        BAR();
        WAIT_LGKM0();
        __builtin_amdgcn_s_setprio(1);
        MFMA_Q(1, 0, bF0);
        __builtin_amdgcn_s_setprio(0);
        if (pf)                 asm volatile("s_waitcnt vmcnt(8)" ::: "memory");
        else if (t + 1 < NT)    asm volatile("s_waitcnt vmcnt(0)" ::: "memory");
        BAR();
    }

    // epilogue: C/D layout col = lane&15, row = quad*4 + reg  [m89/m91-verified]
    // an INNERMOST: each qkv row's 128B written contiguously in time (full-line WC;
    // r8 had an outermost -> WRITE_SIZE 90MB vs 55 logical).
    float  bvs[4];
    size_t cbase[4];   // h,s,d-dependent part of the scatter address
    #pragma unroll
    for (int an = 0; an < 4; ++an) {
        const int cl = tileN + wn * 64 + an * 16 + l16;
        bvs[an] = bias[cl];
        const int s = cl >> 10;
        const int h = (cl >> 6) & (NHEAD - 1);
        const int d = cl & 63;
        cbase[an] = (size_t)(h * 3 + s) * HSLICE + d;
    }
    #pragma unroll
    for (int am = 0; am < 8; ++am) {
        #pragma unroll
        for (int r = 0; r < 4; ++r) {
            const int rowg = tileM + wm * 128 + am * 16 + quad * 4 + r;
            const int b  = rowg >> 11;
            const int tt = rowg & (SEQ - 1);
            const size_t rb = (size_t)b * (NHEAD * 3) * HSLICE + (size_t)tt * HDIM;
            #pragma unroll
            for (int an = 0; an < 4; ++an)
                C[rb + cbase[an]] = __float2bfloat16(acc[am][an][r] + bvs[an]);
        }
    }
}

// ---------------------------------------------------------------------------
// gemm_proj: unchanged 128x128 single-buffer kernel (512 blocks = 2/CU).
// ---------------------------------------------------------------------------
template <int NMAT, typename OutT>
__device__ __forceinline__
void gemm_body(const bf16* __restrict__ A, const bf16* __restrict__ B,
               const float* __restrict__ bias, OutT* __restrict__ C) {
    __shared__ bf16 As[128 * 64];   // 16 KB
    __shared__ bf16 Bs[128 * 64];   // 16 KB

    const int tid  = threadIdx.x;
    const int lane = tid & 63;
    const int wave = tid >> 6;
    const int quad = lane >> 4;
    const int l16  = lane & 15;

    const int tileM = blockIdx.y * 128;
    const int tileN = blockIdx.x * 128;
    const int wm = (wave >> 1) * 64;
    const int wn = (wave & 1) * 64;

    f32x4 acc[4][4] = {};

    for (int kt = 0; kt < KDIM; kt += 64) {
        #pragma unroll
        for (int i = 0; i < 4; ++i) {
            const int c   = i * 256 + tid;
            const int row = c >> 3;
            const int kg  = (c & 7) ^ (row & 7);   // XOR swizzle
            async_copy16(A + (size_t)(tileM + row) * KDIM + kt + kg * 8,
                         (char*)As + c * 16);
            async_copy16(B + (size_t)(tileN + row) * KDIM + kt + kg * 8,
                         (char*)Bs + c * 16);
        }
        __syncthreads();

        #pragma unroll
        for (int ks = 0; ks < 2; ++ks) {
            const int kq = ks * 4 + quad;
            const int so = (kq ^ (l16 & 7)) * 8;
            bf16x8 aF[4], bF[4];
            #pragma unroll
            for (int mt = 0; mt < 4; ++mt)
                aF[mt] = *(const bf16x8*)(As + (wm + mt * 16 + l16) * 64 + so);
            #pragma unroll
            for (int nt = 0; nt < 4; ++nt)
                bF[nt] = *(const bf16x8*)(Bs + (wn + nt * 16 + l16) * 64 + so);

            #pragma unroll
            for (int mt = 0; mt < 4; ++mt)
                #pragma unroll
                for (int nt = 0; nt < 4; ++nt)
                    acc[mt][nt] = __builtin_amdgcn_mfma_f32_16x16x32_bf16(
                        aF[mt], bF[nt], acc[mt][nt], 0, 0, 0);
        }
        __syncthreads();
    }

    #pragma unroll
    for (int nt = 0; nt < 4; ++nt) {
        const int scol = tileN + wn + nt * 16;
        const float bv = bias[scol + l16];
        #pragma unroll
        for (int mt = 0; mt < 4; ++mt) {
            #pragma unroll
            for (int r = 0; r < 4; ++r) {
                const int rowg = tileM + wm + mt * 16 + quad * 4 + r;
                const float v = acc[mt][nt][r] + bv;
                C[(size_t)rowg * NMAT + scol + l16] = v;
            }
        }
    }
}

__global__ __launch_bounds__(256)
void gemm_proj(const bf16* __restrict__ A, const bf16* __restrict__ B,
               const float* __restrict__ bias, float* __restrict__ C) {
    gemm_body<1024, float>(A, B, bias, C);
}

// ---- 8 bf16 (as uint4) -> 8 floats
__device__ __forceinline__ void bf8_to_f32(const uint4 u, float* f) {
    union { uint32_t u; float f; } c;
    c.u = u.x << 16;         f[0] = c.f;
    c.u = u.x & 0xffff0000u; f[1] = c.f;
    c.u = u.y << 16;         f[2] = c.f;
    c.u = u.y & 0xffff0000u; f[3] = c.f;
    c.u = u.z << 16;         f[4] = c.f;
    c.u = u.z & 0xffff0000u; f[5] = c.f;
    c.u = u.w << 16;         f[6] = c.f;
    c.u = u.w & 0xffff0000u; f[7] = c.f;
}

// Banded attention v4 over [b,h,s,t,d] qkv: 4 threads/query (16 dims each).
__global__ __launch_bounds__(256)
void attn_banded4(const bf16* __restrict__ qkv, bf16* __restrict__ aout) {
    const int tid = threadIdx.x;
    const int qi  = tid >> 2;          // 0..63
    const int ch  = tid & 3;           // 16-dim chunk
    const int t   = blockIdx.x * 64 + qi;
    const int h   = blockIdx.y;
    const int b   = blockIdx.z;

    const size_t bh3 = (size_t)(b * NHEAD + h) * 3;
    const bf16* qb = qkv + (bh3 + 0) * HSLICE + (size_t)t * HDIM + ch * 16;
    const bf16* kb = qkv + (bh3 + 1) * HSLICE + ch * 16;
    const bf16* vb = qkv + (bh3 + 2) * HSLICE + ch * 16;
    const float scale = 0.125f;        // hd^-0.5

    float q16[16];
    {
        const uint4* qp = (const uint4*)qb;
        uint4 u0 = qp[0], u1 = qp[1];
        bf8_to_f32(u0, q16); bf8_to_f32(u1, q16 + 8);
    }

    float sc[2 * RADIUS + 1];
    #pragma unroll
    for (int j = 0; j < 2 * RADIUS + 1; ++j) {
        const int k = t - RADIUS + j;
        const bool valid = (k >= 0) && (k < SEQ);
        const int kc = valid ? k : t;
        const uint4* kp = (const uint4*)(kb + (size_t)kc * HDIM);
        float kf[16];
        uint4 u0 = kp[0], u1 = kp[1];
        bf8_to_f32(u0, kf); bf8_to_f32(u1, kf + 8);
        float p = 0.f;
        #pragma unroll
        for (int e = 0; e < 16; ++e) p = fmaf(q16[e], kf[e], p);
        p += __shfl_xor(p, 1, 64);     // merge 4 chunks
        p += __shfl_xor(p, 2, 64);
        sc[j] = valid ? p * scale : -1e30f;
    }

    float mx = sc[0];
    #pragma unroll
    for (int j = 1; j < 2 * RADIUS + 1; ++j) mx = fmaxf(mx, sc[j]);
    float sum = 0.f;
    #pragma unroll
    for (int j = 0; j < 2 * RADIUS + 1; ++j) { sc[j] = __expf(sc[j] - mx); sum += sc[j]; }
    const float inv = 1.0f / sum;

    float o16[16];
    #pragma unroll
    for (int e = 0; e < 16; ++e) o16[e] = 0.f;
    #pragma unroll
    for (int j = 0; j < 2 * RADIUS + 1; ++j) {
        const int k = t - RADIUS + j;
        const int kc = (k >= 0 && k < SEQ) ? k : t;   // weight ~0 when clamped
        const uint4* vp = (const uint4*)(vb + (size_t)kc * HDIM);
        float vf[16];
        uint4 u0 = vp[0], u1 = vp[1];
        bf8_to_f32(u0, vf); bf8_to_f32(u1, vf + 8);
        const float w = sc[j];
        #pragma unroll
        for (int e = 0; e < 16; ++e) o16[e] = fmaf(w, vf[e], o16[e]);
    }

    bf16* op = aout + ((size_t)b * SEQ + t) * DIM + h * HDIM + ch * 16;
    #pragma unroll
    for (int c2 = 0; c2 < 2; ++c2) {
        union { u16x8 v; __hip_bfloat16 hh[8]; } o;
        #pragma unroll
        for (int e = 0; e < 8; ++e) o.hh[e] = __float2bfloat16(o16[c2 * 8 + e] * inv);
        ((u16x8*)op)[c2] = o.v;
    }
}

extern "C" void kernel_launch(void* const* d_in, const int* in_sizes, int n_in,
                              void* d_out, int out_size, void* d_ws, size_t ws_size,
                              hipStream_t stream) {
    const float* x      = (const float*)d_in[0];
    const float* w_qkv  = (const float*)d_in[1];
    const float* b_qkv  = (const float*)d_in[2];
    const float* w_proj = (const float*)d_in[3];
    const float* b_proj = (const float*)d_in[4];
    float* out = (float*)d_out;

    bf16* xb     = (bf16*)d_ws;
    bf16* wqkvb  = xb + (size_t)ROWS * DIM;
    bf16* wprojb = wqkvb + (size_t)3072 * 1024;
    bf16* qkvb   = wprojb + (size_t)1024 * 1024;   // [b,h,s,t,d], 48 MiB
    bf16* attnb  = qkvb + (size_t)ROWS * 3072;

    const int n1 = ROWS * DIM / 8, n2 = 3072 * 1024 / 8, n3 = 1024 * 1024 / 8;
    cvt_all<<<(n1 + n2 + n3 + 255) / 256, 256, 0, stream>>>(x, xb, n1, w_qkv, wqkvb, n2,
                                                            w_proj, wprojb, n3);

    // GEMM1: 8-phase 256x256 template, 384 blocks (32 Mtiles x 12 Ntiles)
    gemm_qkv_8p<<<dim3(384), 512, 0, stream>>>(xb, wqkvb, b_qkv, qkvb);

    // attn v4: 4 threads/query, 32 waves/CU
    attn_banded4<<<dim3(SEQ / 64, NHEAD, BATCH), 256, 0, stream>>>(qkvb, attnb);

    // GEMM2: 128x128 tiles, 512 blocks
    gemm_proj<<<dim3(1024 / 128, ROWS / 128), 256, 0, stream>>>(attnb, wprojb, b_proj, out);
}

// Round 4
// 198.959 us; speedup vs baseline: 1.0596x; 1.0185x over previous
//
#include <hip/hip_runtime.h>
#include <hip/hip_bf16.h>
#include <cstdint>
#include <cstddef>
#include <type_traits>

// FocalAttention: B=4 T=2048 D=1024 H=16 hd=64 RADIUS=4 (banded, 9-wide window)
// fp32 in/out. cvt(fp32->bf16) -> gemm_qkv (8-phase 256x192) -> banded attn
// (4 threads/query) -> gemm_proj 128x128 (fp32 out).
// r7 lesson: never split the 128x128 GEMM grid below ~4 blocks/CU.
// r8 lesson: sched_barrier(0) around every barrier = m141 regression (0.55x).
// r9 lesson: bare-barrier 8-phase @256x256 = 72.5us, but 384 blocks = 1.5 rounds
//   -> 25% idle tax (per-block 5150 cyc/K-tile vs m201's 3300 busy-equivalent).
// r10: BN 256->192, grid 32x16 = 512 blocks = EXACTLY 2 rounds.
//   Phases {16,8,8,16} MFMA, reads {12,2,8,0}; 7 stage-units/K-tile -> vmcnt(7).
// r11 (this round): r10 bench was an infra failure ("container failed twice",
//   no verify output). Audit found no hang/OOB/divergent-barrier path ->
//   resubmitting r10 unchanged.

typedef __hip_bfloat16 bf16;
typedef __attribute__((ext_vector_type(8))) short bf16x8;   // A/B frag: 8 bf16 = 4 VGPRs
typedef __attribute__((ext_vector_type(4))) float f32x4;    // C/D frag
typedef __attribute__((ext_vector_type(8))) unsigned short u16x8;

#define BATCH  4
#define SEQ    2048
#define DIM    1024
#define NHEAD  16
#define HDIM   64
#define RADIUS 4
#define ROWS   (BATCH * SEQ)          // 8192
#define KDIM   1024
#define NT     (KDIM / 64)            // 16 K-tiles
#define HSLICE (SEQ * HDIM)           // elems per (b,h,s) slice

__device__ __forceinline__ void async_copy16(const void* gptr, void* lptr) {
    __builtin_amdgcn_global_load_lds(
        (const __attribute__((address_space(1))) unsigned int*)(uintptr_t)gptr,
        (__attribute__((address_space(3))) unsigned int*)(uint32_t)(uintptr_t)lptr,
        16, 0, 0);
}

// Fused fp32 -> bf16 convert for all three tensors, 8 elems/thread.
__global__ __launch_bounds__(256)
void cvt_all(const float* __restrict__ s1, bf16* __restrict__ d1, int n1,
             const float* __restrict__ s2, bf16* __restrict__ d2, int n2,
             const float* __restrict__ s3, bf16* __restrict__ d3, int n3) {
    int i = blockIdx.x * blockDim.x + threadIdx.x;
    const float* src; bf16* dst;
    if (i < n1)              { src = s1; dst = d1; }
    else if (i < n1 + n2)    { i -= n1; src = s2; dst = d2; }
    else if (i < n1+n2+n3)   { i -= n1 + n2; src = s3; dst = d3; }
    else return;
    const float4 a = ((const float4*)src)[2 * i];
    const float4 b = ((const float4*)src)[2 * i + 1];
    union { u16x8 v; __hip_bfloat16 h[8]; } o;
    o.h[0] = __float2bfloat16(a.x); o.h[1] = __float2bfloat16(a.y);
    o.h[2] = __float2bfloat16(a.z); o.h[3] = __float2bfloat16(a.w);
    o.h[4] = __float2bfloat16(b.x); o.h[5] = __float2bfloat16(b.y);
    o.h[6] = __float2bfloat16(b.z); o.h[7] = __float2bfloat16(b.w);
    ((u16x8*)dst)[i] = o.v;
}

// ---------------------------------------------------------------------------
// gemm_qkv: 8-phase 256x192 template. C[row][col] = A[row,:] . B[col,:] + bias,
// scattered to qkv [b,h,s,t,d] layout in bf16.
// Schedule invariants (re-derived for BN=192):
//   - stage units/K-tile: A=4 (64 rows each), B=3 (64 rows each) = 7.
//   - B buf(t) region last ds_read = P2 (bFB slabs) -> B(t+2) stages in P3.
//     A buf(t) last ds_read = P3 (LDA1)            -> A(t+2) stages in P4.
//   - at P4 wait: 7 in flight from t+1 + 7 issued this tile -> vmcnt(7)
//     drains exactly tile t+1, keeps t+2 in flight.
//   - tail: vmcnt(0) at t=NT-2, nothing at t=NT-1.
//   - cross-wave WAR safety: each wave drains lgkmcnt(0) before reaching the
//     phase-end barrier, so any post-barrier stage sees all reads complete.
// ---------------------------------------------------------------------------

#define BAR()        __builtin_amdgcn_s_barrier()
#define WAIT_LGKM0() asm volatile("s_waitcnt lgkmcnt(0)")

#define STAGE_A(buf_, half_, kt_) do {                                          \
    _Pragma("unroll")                                                           \
    for (int i_ = 0; i_ < 2; ++i_) {                                            \
        const int c_   = i_ * 512 + tid;                                        \
        const int row_ = (half_) * 128 + (c_ >> 3);                             \
        const int kg_  = (c_ & 7) ^ (row_ & 7);                                 \
        async_copy16(A + (size_t)(tileM + row_) * KDIM + (kt_) + kg_ * 8,       \
                     (char*)As[buf_] + ((half_) * 1024 + c_) * 16);             \
    } } while (0)

// B tile = 192 rows x 64 k = 24 KB = 3 units of 512 thr x 16 B.
#define STAGE_B3(buf_, kt_) do {                                                \
    _Pragma("unroll")                                                           \
    for (int j_ = 0; j_ < 3; ++j_) {                                            \
        const int c_   = j_ * 512 + tid;                                        \
        const int row_ = c_ >> 3;                                               \
        const int kg_  = (c_ & 7) ^ (row_ & 7);                                 \
        async_copy16(B + (size_t)(tileN + row_) * KDIM + (kt_) + kg_ * 8,       \
                     (char*)Bs[buf_] + c_ * 16);                                \
    } } while (0)

// LDS -> register fragments (swizzled read side; row%8 == l16%8 since 48,16,64,128 ≡0 mod 8)
#define LDA_Q(mh_) do {                                                         \
    _Pragma("unroll")                                                           \
    for (int ks_ = 0; ks_ < 2; ++ks_)                                           \
    _Pragma("unroll")                                                           \
    for (int mt_ = 0; mt_ < 4; ++mt_)                                           \
        aF[ks_][mt_] = *(const bf16x8*)(as_ +                                   \
            (size_t)(wm * 128 + (mh_) * 64 + mt_ * 16 + l16) * 64 +             \
            ((((ks_ << 2) | quad) ^ hh) << 3));                                 \
} while (0)

// bFA: nt 0,1 (4 reads). bFB: nt 2 (2 reads).
#define LDB_A() do {                                                            \
    _Pragma("unroll")                                                           \
    for (int ks_ = 0; ks_ < 2; ++ks_)                                           \
    _Pragma("unroll")                                                           \
    for (int nt_ = 0; nt_ < 2; ++nt_)                                           \
        bFA[ks_][nt_] = *(const bf16x8*)(bs_ +                                  \
            (size_t)(wn * 48 + nt_ * 16 + l16) * 64 +                           \
            ((((ks_ << 2) | quad) ^ hh) << 3));                                 \
} while (0)

#define LDB_B() do {                                                            \
    _Pragma("unroll")                                                           \
    for (int ks_ = 0; ks_ < 2; ++ks_)                                           \
        bFB[ks_] = *(const bf16x8*)(bs_ +                                       \
            (size_t)(wn * 48 + 32 + l16) * 64 +                                 \
            ((((ks_ << 2) | quad) ^ hh) << 3));                                 \
} while (0)

// 16-MFMA cluster: m-half mh x nt{0,1} over K=64.
#define MFMA_N01(mh_) do {                                                      \
    _Pragma("unroll")                                                           \
    for (int ks_ = 0; ks_ < 2; ++ks_)                                           \
    _Pragma("unroll")                                                           \
    for (int mt_ = 0; mt_ < 4; ++mt_)                                           \
    _Pragma("unroll")                                                           \
    for (int nt_ = 0; nt_ < 2; ++nt_)                                           \
        acc[(mh_) * 4 + mt_][nt_] = __builtin_amdgcn_mfma_f32_16x16x32_bf16(    \
            aF[ks_][mt_], bFA[ks_][nt_], acc[(mh_) * 4 + mt_][nt_], 0, 0, 0);   \
} while (0)

// 8-MFMA cluster: m-half mh x nt{2} over K=64.
#define MFMA_N2(mh_) do {                                                       \
    _Pragma("unroll")                                                           \
    for (int ks_ = 0; ks_ < 2; ++ks_)                                           \
    _Pragma("unroll")                                                           \
    for (int mt_ = 0; mt_ < 4; ++mt_)                                           \
        acc[(mh_) * 4 + mt_][2] = __builtin_amdgcn_mfma_f32_16x16x32_bf16(      \
            aF[ks_][mt_], bFB[ks_], acc[(mh_) * 4 + mt_][2], 0, 0, 0);          \
} while (0)

__global__ __launch_bounds__(512, 1)
void gemm_qkv_8p(const bf16* __restrict__ A, const bf16* __restrict__ B,
                 const float* __restrict__ bias, bf16* __restrict__ C) {
    __shared__ bf16 As[2][256 * 64];   // 64 KB
    __shared__ bf16 Bs[2][192 * 64];   // 48 KB  (112 KB total -> 1 block/CU)

    const int tid  = threadIdx.x;
    const int l16  = tid & 15;
    const int quad = (tid >> 4) & 3;
    const int wave = tid >> 6;          // 0..7
    const int wm   = wave >> 2;         // 0..1  (M split)
    const int wn   = wave & 3;          // 0..3  (N split, 48 cols each)
    const int hh   = l16 & 7;

    // XCD-aware swizzle: grid = 512 = 32 Mtiles x 16 Ntiles; 512 % 8 == 0 -> bijective.
    const int bid = (int)blockIdx.x;
    const int seq = (bid & 7) * 64 + (bid >> 3);
    const int tileM = (seq >> 4) * 256;
    const int tileN = (seq & 15) * 192;

    f32x4  acc[8][3] = {};
    bf16x8 aF[2][4], bFA[2][2], bFB[2];

    // prologue: stage tiles 0 and 1 fully (14 units); drain tile 0 -> vmcnt(7)
    STAGE_A(0, 0, 0);  STAGE_A(0, 1, 0);  STAGE_B3(0, 0);
    STAGE_A(1, 0, 64); STAGE_A(1, 1, 64); STAGE_B3(1, 64);
    asm volatile("s_waitcnt vmcnt(7)" ::: "memory");
    BAR();

    #pragma unroll 1
    for (int t = 0; t < NT; ++t) {
        const int buf = t & 1;
        const bf16* __restrict__ as_ = &As[buf][0];
        const bf16* __restrict__ bs_ = &Bs[buf][0];
        const int  kt2 = (t + 2) * 64;
        const bool pf  = (t + 2 < NT);

        // ---- P1: (m0, nt01); 12 ds_read_b128 ----
        LDA_Q(0);
        LDB_A();
        asm volatile("s_waitcnt lgkmcnt(8)");   // template hint (12 issued)
        BAR();
        WAIT_LGKM0();
        __builtin_amdgcn_s_setprio(1);
        MFMA_N01(0);
        __builtin_amdgcn_s_setprio(0);
        BAR();

        // ---- P2: (m0, nt2); 2 ds_read_b128 ----
        LDB_B();
        BAR();
        WAIT_LGKM0();
        __builtin_amdgcn_s_setprio(1);
        MFMA_N2(0);
        __builtin_amdgcn_s_setprio(0);
        BAR();

        // ---- P3: (m1, nt2); 8 ds_read_b128; stage B(t+2) (B reads done @P2) ----
        LDA_Q(1);
        if (pf) STAGE_B3(buf, kt2);
        BAR();
        WAIT_LGKM0();
        __builtin_amdgcn_s_setprio(1);
        MFMA_N2(1);
        __builtin_amdgcn_s_setprio(0);
        BAR();

        // ---- P4: (m1, nt01); stage A(t+2) (A reads done @P3); counted drain ----
        // no new ds_reads this phase: aF drained @P3, bFA drained @P1.
        if (pf) { STAGE_A(buf, 0, kt2); STAGE_A(buf, 1, kt2); }
        BAR();
        __builtin_amdgcn_s_setprio(1);
        MFMA_N01(1);
        __builtin_amdgcn_s_setprio(0);
        if (pf)                 asm volatile("s_waitcnt vmcnt(7)" ::: "memory");
        else if (t + 1 < NT)    asm volatile("s_waitcnt vmcnt(0)" ::: "memory");
        BAR();
    }

    // epilogue: C/D layout col = lane&15, row = quad*4 + reg  [m89/m91-verified]
    // an INNERMOST: each qkv row written contiguously in time (full-line WC, r9).
    float  bvs[3];
    size_t cbase[3];   // h,s,d-dependent part of the scatter address
    #pragma unroll
    for (int an = 0; an < 3; ++an) {
        const int cl = tileN + wn * 48 + an * 16 + l16;
        bvs[an] = bias[cl];
        const int s = cl >> 10;
        const int h = (cl >> 6) & (NHEAD - 1);
        const int d = cl & 63;
        cbase[an] = (size_t)(h * 3 + s) * HSLICE + d;
    }
    #pragma unroll
    for (int am = 0; am < 8; ++am) {
        #pragma unroll
        for (int r = 0; r < 4; ++r) {
            const int rowg = tileM + wm * 128 + am * 16 + quad * 4 + r;
            const int b  = rowg >> 11;
            const int tt = rowg & (SEQ - 1);
            const size_t rb = (size_t)b * (NHEAD * 3) * HSLICE + (size_t)tt * HDIM;
            #pragma unroll
            for (int an = 0; an < 3; ++an)
                C[rb + cbase[an]] = __float2bfloat16(acc[am][an][r] + bvs[an]);
        }
    }
}

// ---------------------------------------------------------------------------
// gemm_proj: unchanged 128x128 single-buffer kernel (512 blocks = 2/CU).
// ---------------------------------------------------------------------------
template <int NMAT, typename OutT>
__device__ __forceinline__
void gemm_body(const bf16* __restrict__ A, const bf16* __restrict__ B,
               const float* __restrict__ bias, OutT* __restrict__ C) {
    __shared__ bf16 As[128 * 64];   // 16 KB
    __shared__ bf16 Bs[128 * 64];   // 16 KB

    const int tid  = threadIdx.x;
    const int lane = tid & 63;
    const int wave = tid >> 6;
    const int quad = lane >> 4;
    const int l16  = lane & 15;

    const int tileM = blockIdx.y * 128;
    const int tileN = blockIdx.x * 128;
    const int wm = (wave >> 1) * 64;
    const int wn = (wave & 1) * 64;

    f32x4 acc[4][4] = {};

    for (int kt = 0; kt < KDIM; kt += 64) {
        #pragma unroll
        for (int i = 0; i < 4; ++i) {
            const int c   = i * 256 + tid;
            const int row = c >> 3;
            const int kg  = (c & 7) ^ (row & 7);   // XOR swizzle
            async_copy16(A + (size_t)(tileM + row) * KDIM + kt + kg * 8,
                         (char*)As + c * 16);
            async_copy16(B + (size_t)(tileN + row) * KDIM + kt + kg * 8,
                         (char*)Bs + c * 16);
        }
        __syncthreads();

        #pragma unroll
        for (int ks = 0; ks < 2; ++ks) {
            const int kq = ks * 4 + quad;
            const int so = (kq ^ (l16 & 7)) * 8;
            bf16x8 aF[4], bF[4];
            #pragma unroll
            for (int mt = 0; mt < 4; ++mt)
                aF[mt] = *(const bf16x8*)(As + (wm + mt * 16 + l16) * 64 + so);
            #pragma unroll
            for (int nt = 0; nt < 4; ++nt)
                bF[nt] = *(const bf16x8*)(Bs + (wn + nt * 16 + l16) * 64 + so);

            #pragma unroll
            for (int mt = 0; mt < 4; ++mt)
                #pragma unroll
                for (int nt = 0; nt < 4; ++nt)
                    acc[mt][nt] = __builtin_amdgcn_mfma_f32_16x16x32_bf16(
                        aF[mt], bF[nt], acc[mt][nt], 0, 0, 0);
        }
        __syncthreads();
    }

    #pragma unroll
    for (int nt = 0; nt < 4; ++nt) {
        const int scol = tileN + wn + nt * 16;
        const float bv = bias[scol + l16];
        #pragma unroll
        for (int mt = 0; mt < 4; ++mt) {
            #pragma unroll
            for (int r = 0; r < 4; ++r) {
                const int rowg = tileM + wm + mt * 16 + quad * 4 + r;
                const float v = acc[mt][nt][r] + bv;
                C[(size_t)rowg * NMAT + scol + l16] = v;
            }
        }
    }
}

__global__ __launch_bounds__(256)
void gemm_proj(const bf16* __restrict__ A, const bf16* __restrict__ B,
               const float* __restrict__ bias, float* __restrict__ C) {
    gemm_body<1024, float>(A, B, bias, C);
}

// ---- 8 bf16 (as uint4) -> 8 floats
__device__ __forceinline__ void bf8_to_f32(const uint4 u, float* f) {
    union { uint32_t u; float f; } c;
    c.u = u.x << 16;         f[0] = c.f;
    c.u = u.x & 0xffff0000u; f[1] = c.f;
    c.u = u.y << 16;         f[2] = c.f;
    c.u = u.y & 0xffff0000u; f[3] = c.f;
    c.u = u.z << 16;         f[4] = c.f;
    c.u = u.z & 0xffff0000u; f[5] = c.f;
    c.u = u.w << 16;         f[6] = c.f;
    c.u = u.w & 0xffff0000u; f[7] = c.f;
}

// Banded attention v4 over [b,h,s,t,d] qkv: 4 threads/query (16 dims each).
__global__ __launch_bounds__(256)
void attn_banded4(const bf16* __restrict__ qkv, bf16* __restrict__ aout) {
    const int tid = threadIdx.x;
    const int qi  = tid >> 2;          // 0..63
    const int ch  = tid & 3;           // 16-dim chunk
    const int t   = blockIdx.x * 64 + qi;
    const int h   = blockIdx.y;
    const int b   = blockIdx.z;

    const size_t bh3 = (size_t)(b * NHEAD + h) * 3;
    const bf16* qb = qkv + (bh3 + 0) * HSLICE + (size_t)t * HDIM + ch * 16;
    const bf16* kb = qkv + (bh3 + 1) * HSLICE + ch * 16;
    const bf16* vb = qkv + (bh3 + 2) * HSLICE + ch * 16;
    const float scale = 0.125f;        // hd^-0.5

    float q16[16];
    {
        const uint4* qp = (const uint4*)qb;
        uint4 u0 = qp[0], u1 = qp[1];
        bf8_to_f32(u0, q16); bf8_to_f32(u1, q16 + 8);
    }

    float sc[2 * RADIUS + 1];
    #pragma unroll
    for (int j = 0; j < 2 * RADIUS + 1; ++j) {
        const int k = t - RADIUS + j;
        const bool valid = (k >= 0) && (k < SEQ);
        const int kc = valid ? k : t;
        const uint4* kp = (const uint4*)(kb + (size_t)kc * HDIM);
        float kf[16];
        uint4 u0 = kp[0], u1 = kp[1];
        bf8_to_f32(u0, kf); bf8_to_f32(u1, kf + 8);
        float p = 0.f;
        #pragma unroll
        for (int e = 0; e < 16; ++e) p = fmaf(q16[e], kf[e], p);
        p += __shfl_xor(p, 1, 64);     // merge 4 chunks
        p += __shfl_xor(p, 2, 64);
        sc[j] = valid ? p * scale : -1e30f;
    }

    float mx = sc[0];
    #pragma unroll
    for (int j = 1; j < 2 * RADIUS + 1; ++j) mx = fmaxf(mx, sc[j]);
    float sum = 0.f;
    #pragma unroll
    for (int j = 0; j < 2 * RADIUS + 1; ++j) { sc[j] = __expf(sc[j] - mx); sum += sc[j]; }
    const float inv = 1.0f / sum;

    float o16[16];
    #pragma unroll
    for (int e = 0; e < 16; ++e) o16[e] = 0.f;
    #pragma unroll
    for (int j = 0; j < 2 * RADIUS + 1; ++j) {
        const int k = t - RADIUS + j;
        const int kc = (k >= 0 && k < SEQ) ? k : t;   // weight ~0 when clamped
        const uint4* vp = (const uint4*)(vb + (size_t)kc * HDIM);
        float vf[16];
        uint4 u0 = vp[0], u1 = vp[1];
        bf8_to_f32(u0, vf); bf8_to_f32(u1, vf + 8);
        const float w = sc[j];
        #pragma unroll
        for (int e = 0; e < 16; ++e) o16[e] = fmaf(w, vf[e], o16[e]);
    }

    bf16* op = aout + ((size_t)b * SEQ + t) * DIM + h * HDIM + ch * 16;
    #pragma unroll
    for (int c2 = 0; c2 < 2; ++c2) {
        union { u16x8 v; __hip_bfloat16 hh[8]; } o;
        #pragma unroll
        for (int e = 0; e < 8; ++e) o.hh[e] = __float2bfloat16(o16[c2 * 8 + e] * inv);
        ((u16x8*)op)[c2] = o.v;
    }
}

extern "C" void kernel_launch(void* const* d_in, const int* in_sizes, int n_in,
                              void* d_out, int out_size, void* d_ws, size_t ws_size,
                              hipStream_t stream) {
    const float* x      = (const float*)d_in[0];
    const float* w_qkv  = (const float*)d_in[1];
    const float* b_qkv  = (const float*)d_in[2];
    const float* w_proj = (const float*)d_in[3];
    const float* b_proj = (const float*)d_in[4];
    float* out = (float*)d_out;

    bf16* xb     = (bf16*)d_ws;
    bf16* wqkvb  = xb + (size_t)ROWS * DIM;
    bf16* wprojb = wqkvb + (size_t)3072 * 1024;
    bf16* qkvb   = wprojb + (size_t)1024 * 1024;   // [b,h,s,t,d], 48 MiB
    bf16* attnb  = qkvb + (size_t)ROWS * 3072;

    const int n1 = ROWS * DIM / 8, n2 = 3072 * 1024 / 8, n3 = 1024 * 1024 / 8;
    cvt_all<<<(n1 + n2 + n3 + 255) / 256, 256, 0, stream>>>(x, xb, n1, w_qkv, wqkvb, n2,
                                                            w_proj, wprojb, n3);

    // GEMM1: 8-phase 256x192 template, 512 blocks (32 Mtiles x 16 Ntiles) = 2.0 rounds
    gemm_qkv_8p<<<dim3(512), 512, 0, stream>>>(xb, wqkvb, b_qkv, qkvb);

    // attn v4: 4 threads/query, 32 waves/CU
    attn_banded4<<<dim3(SEQ / 64, NHEAD, BATCH), 256, 0, stream>>>(qkvb, attnb);

    // GEMM2: 128x128 tiles, 512 blocks
    gemm_proj<<<dim3(1024 / 128, ROWS / 128), 256, 0, stream>>>(attnb, wprojb, b_proj, out);
}

// Round 5
// 191.722 us; speedup vs baseline: 1.0996x; 1.0377x over previous
//
#include <hip/hip_runtime.h>
#include <hip/hip_bf16.h>
#include <cstdint>
#include <cstddef>
#include <type_traits>

// FocalAttention: B=4 T=2048 D=1024 H=16 hd=64 RADIUS=4 (banded, 9-wide window)
// fp32 in/out. cvt(fp32->bf16) -> gemm_qkv (2-phase 128x192, 2 blocks/CU) ->
// banded attn (4 threads/query) -> gemm_proj 128x128 (fp32 out).
// r8 lesson: sched_barrier(0) around every barrier = m141 regression (0.55x).
// r9 lesson: 8-phase 256x256 @384 blocks = 1.5 rounds -> 25% idle tax.
// r10/r12 lesson: 8-phase 256x192 @512 blocks = 65.9us, MfmaUtil 31%; at
//   1 block/CU the phase skeleton is intra-block serial (reads|barrier|MFMA)
//   and K=1024 can't amortize it (non-MFMA 3375 cyc/K-tile vs m201's 1250).
// r13 (this round): BM=128 BN=192, LDS 80KB -> 2 blocks/CU (4 waves/SIMD).
//   Cross-block TLP overlaps read phases with the co-resident block's MFMA
//   (m114/m97 mechanism). 2 phases/K-tile; counted vmcnt(2); launch_bounds(512,4).
//   Ledger: stage units A=2,B=3; B(t+1)@P1(t), A(t+2)@P2(t);
//   outstanding at P2-end = 2+3+2=7 -> vmcnt(2) drains exactly tile t+1.

typedef __hip_bfloat16 bf16;
typedef __attribute__((ext_vector_type(8))) short bf16x8;   // A/B frag: 8 bf16 = 4 VGPRs
typedef __attribute__((ext_vector_type(4))) float f32x4;    // C/D frag
typedef __attribute__((ext_vector_type(8))) unsigned short u16x8;

#define BATCH  4
#define SEQ    2048
#define DIM    1024
#define NHEAD  16
#define HDIM   64
#define RADIUS 4
#define ROWS   (BATCH * SEQ)          // 8192
#define KDIM   1024
#define NT     (KDIM / 64)            // 16 K-tiles
#define HSLICE (SEQ * HDIM)           // elems per (b,h,s) slice

__device__ __forceinline__ void async_copy16(const void* gptr, void* lptr) {
    __builtin_amdgcn_global_load_lds(
        (const __attribute__((address_space(1))) unsigned int*)(uintptr_t)gptr,
        (__attribute__((address_space(3))) unsigned int*)(uint32_t)(uintptr_t)lptr,
        16, 0, 0);
}

// Fused fp32 -> bf16 convert for all three tensors, 8 elems/thread.
__global__ __launch_bounds__(256)
void cvt_all(const float* __restrict__ s1, bf16* __restrict__ d1, int n1,
             const float* __restrict__ s2, bf16* __restrict__ d2, int n2,
             const float* __restrict__ s3, bf16* __restrict__ d3, int n3) {
    int i = blockIdx.x * blockDim.x + threadIdx.x;
    const float* src; bf16* dst;
    if (i < n1)              { src = s1; dst = d1; }
    else if (i < n1 + n2)    { i -= n1; src = s2; dst = d2; }
    else if (i < n1+n2+n3)   { i -= n1 + n2; src = s3; dst = d3; }
    else return;
    const float4 a = ((const float4*)src)[2 * i];
    const float4 b = ((const float4*)src)[2 * i + 1];
    union { u16x8 v; __hip_bfloat16 h[8]; } o;
    o.h[0] = __float2bfloat16(a.x); o.h[1] = __float2bfloat16(a.y);
    o.h[2] = __float2bfloat16(a.z); o.h[3] = __float2bfloat16(a.w);
    o.h[4] = __float2bfloat16(b.x); o.h[5] = __float2bfloat16(b.y);
    o.h[6] = __float2bfloat16(b.z); o.h[7] = __float2bfloat16(b.w);
    ((u16x8*)dst)[i] = o.v;
}

// ---------------------------------------------------------------------------
// gemm_qkv: 2-phase 128x192 tile, 2 blocks/CU. C = A[M,K]*B[N,K]^T + bias,
// scattered to qkv [b,h,s,t,d] layout in bf16.
// ---------------------------------------------------------------------------

#define BAR()        __builtin_amdgcn_s_barrier()
#define WAIT_LGKM0() asm volatile("s_waitcnt lgkmcnt(0)")

// A tile = 128 rows x 64 k = 16 KB = 2 units of 512 thr x 16 B.
#define STAGE_A2(buf_, kt_) do {                                                \
    _Pragma("unroll")                                                           \
    for (int i_ = 0; i_ < 2; ++i_) {                                            \
        const int c_   = i_ * 512 + tid;                                        \
        const int row_ = c_ >> 3;                                               \
        const int kg_  = (c_ & 7) ^ (row_ & 7);                                 \
        async_copy16(A + (size_t)(tileM + row_) * KDIM + (kt_) + kg_ * 8,       \
                     (char*)As[buf_] + c_ * 16);                                \
    } } while (0)

// B tile = 192 rows x 64 k = 24 KB = 3 units of 512 thr x 16 B.
#define STAGE_B3(buf_, kt_) do {                                                \
    _Pragma("unroll")                                                           \
    for (int j_ = 0; j_ < 3; ++j_) {                                            \
        const int c_   = j_ * 512 + tid;                                        \
        const int row_ = c_ >> 3;                                               \
        const int kg_  = (c_ & 7) ^ (row_ & 7);                                 \
        async_copy16(B + (size_t)(tileN + row_) * KDIM + (kt_) + kg_ * 8,       \
                     (char*)Bs[buf_] + c_ * 16);                                \
    } } while (0)

// LDS -> register fragments (swizzled read side; same verified-0-conflict form)
#define LDA8() do {                                                             \
    _Pragma("unroll")                                                           \
    for (int ks_ = 0; ks_ < 2; ++ks_)                                           \
    _Pragma("unroll")                                                           \
    for (int mt_ = 0; mt_ < 4; ++mt_)                                           \
        aF[ks_][mt_] = *(const bf16x8*)(as_ +                                   \
            (size_t)(wm * 64 + mt_ * 16 + l16) * 64 +                           \
            ((((ks_ << 2) | quad) ^ hh) << 3));                                 \
} while (0)

#define LDBA() do {                                                             \
    _Pragma("unroll")                                                           \
    for (int ks_ = 0; ks_ < 2; ++ks_)                                           \
    _Pragma("unroll")                                                           \
    for (int nt_ = 0; nt_ < 2; ++nt_)                                           \
        bFA[ks_][nt_] = *(const bf16x8*)(bs_ +                                  \
            (size_t)(wn * 48 + nt_ * 16 + l16) * 64 +                           \
            ((((ks_ << 2) | quad) ^ hh) << 3));                                 \
} while (0)

#define LDBB() do {                                                             \
    _Pragma("unroll")                                                           \
    for (int ks_ = 0; ks_ < 2; ++ks_)                                           \
        bFB[ks_] = *(const bf16x8*)(bs_ +                                       \
            (size_t)(wn * 48 + 32 + l16) * 64 +                                 \
            ((((ks_ << 2) | quad) ^ hh) << 3));                                 \
} while (0)

// 16-MFMA cluster: mt x nt{0,1} over K=64.
#define MFMA_N01() do {                                                         \
    _Pragma("unroll")                                                           \
    for (int ks_ = 0; ks_ < 2; ++ks_)                                           \
    _Pragma("unroll")                                                           \
    for (int mt_ = 0; mt_ < 4; ++mt_)                                           \
    _Pragma("unroll")                                                           \
    for (int nt_ = 0; nt_ < 2; ++nt_)                                           \
        acc[mt_][nt_] = __builtin_amdgcn_mfma_f32_16x16x32_bf16(                \
            aF[ks_][mt_], bFA[ks_][nt_], acc[mt_][nt_], 0, 0, 0);               \
} while (0)

// 8-MFMA cluster: mt x nt{2} over K=64.
#define MFMA_N2() do {                                                          \
    _Pragma("unroll")                                                           \
    for (int ks_ = 0; ks_ < 2; ++ks_)                                           \
    _Pragma("unroll")                                                           \
    for (int mt_ = 0; mt_ < 4; ++mt_)                                           \
        acc[mt_][2] = __builtin_amdgcn_mfma_f32_16x16x32_bf16(                  \
            aF[ks_][mt_], bFB[ks_], acc[mt_][2], 0, 0, 0);                      \
} while (0)

__global__ __launch_bounds__(512, 4)   // 4 waves/SIMD -> 2 blocks/CU
void gemm_qkv_2b(const bf16* __restrict__ A, const bf16* __restrict__ B,
                 const float* __restrict__ bias, bf16* __restrict__ C) {
    __shared__ bf16 As[2][128 * 64];   // 32 KB
    __shared__ bf16 Bs[2][192 * 64];   // 48 KB  (80 KB total -> 2 blocks/CU)

    const int tid  = threadIdx.x;
    const int l16  = tid & 15;
    const int quad = (tid >> 4) & 3;
    const int wave = tid >> 6;          // 0..7
    const int wm   = wave >> 2;         // 0..1  (M split, 64 rows each)
    const int wn   = wave & 3;          // 0..3  (N split, 48 cols each)
    const int hh   = l16 & 7;

    // XCD-aware swizzle: grid = 1024 = 64 Mtiles x 16 Ntiles; 1024 % 8 == 0.
    const int bid = (int)blockIdx.x;
    const int seq = (bid & 7) * 128 + (bid >> 3);
    const int tileM = (seq >> 4) * 128;
    const int tileN = (seq & 15) * 192;

    f32x4  acc[4][3] = {};
    bf16x8 aF[2][4], bFA[2][2], bFB[2];

    // prologue: A(0),B(0),A(1) = 7 units; tile0 = first 5 -> vmcnt(2)
    STAGE_A2(0, 0);  STAGE_B3(0, 0);  STAGE_A2(1, 64);
    asm volatile("s_waitcnt vmcnt(2)" ::: "memory");
    BAR();

    #pragma unroll 1
    for (int t = 0; t < NT; ++t) {
        const int buf = t & 1;
        const bf16* __restrict__ as_ = &As[buf][0];
        const bf16* __restrict__ bs_ = &Bs[buf][0];

        // ---- P1: 12 ds_read_b128; stage B(t+1) (region last read P2(t-1)) ----
        LDA8();
        LDBA();
        if (t + 1 < NT) STAGE_B3(buf ^ 1, (t + 1) * 64);
        asm volatile("s_waitcnt lgkmcnt(8)");   // template hint (12 issued)
        BAR();
        WAIT_LGKM0();
        __builtin_amdgcn_s_setprio(1);
        MFMA_N01();
        __builtin_amdgcn_s_setprio(0);
        BAR();

        // ---- P2: 2 ds_read_b128; stage A(t+2) (A(t) reads done @P1) ----
        LDBB();
        if (t + 2 < NT) STAGE_A2(buf, (t + 2) * 64);
        BAR();
        WAIT_LGKM0();
        __builtin_amdgcn_s_setprio(1);
        MFMA_N2();
        __builtin_amdgcn_s_setprio(0);
        // counted drain: keep A(t+2) in flight; tail drains fully at t=NT-2
        if (t + 2 < NT)         asm volatile("s_waitcnt vmcnt(2)" ::: "memory");
        else if (t + 1 < NT)    asm volatile("s_waitcnt vmcnt(0)" ::: "memory");
        BAR();
    }

    // epilogue: C/D layout col = lane&15, row = quad*4 + reg  [m89/m91-verified]
    // an INNERMOST: each qkv row written contiguously in time (full-line WC, r9).
    float  bvs[3];
    size_t cbase[3];   // h,s,d-dependent part of the scatter address
    #pragma unroll
    for (int an = 0; an < 3; ++an) {
        const int cl = tileN + wn * 48 + an * 16 + l16;
        bvs[an] = bias[cl];
        const int s = cl >> 10;
        const int h = (cl >> 6) & (NHEAD - 1);
        const int d = cl & 63;
        cbase[an] = (size_t)(h * 3 + s) * HSLICE + d;
    }
    #pragma unroll
    for (int mt = 0; mt < 4; ++mt) {
        #pragma unroll
        for (int r = 0; r < 4; ++r) {
            const int rowg = tileM + wm * 64 + mt * 16 + quad * 4 + r;
            const int b  = rowg >> 11;
            const int tt = rowg & (SEQ - 1);
            const size_t rb = (size_t)b * (NHEAD * 3) * HSLICE + (size_t)tt * HDIM;
            #pragma unroll
            for (int an = 0; an < 3; ++an)
                C[rb + cbase[an]] = __float2bfloat16(acc[mt][an][r] + bvs[an]);
        }
    }
}

// ---------------------------------------------------------------------------
// gemm_proj: unchanged 128x128 single-buffer kernel (512 blocks = 2/CU).
// ---------------------------------------------------------------------------
template <int NMAT, typename OutT>
__device__ __forceinline__
void gemm_body(const bf16* __restrict__ A, const bf16* __restrict__ B,
               const float* __restrict__ bias, OutT* __restrict__ C) {
    __shared__ bf16 As[128 * 64];   // 16 KB
    __shared__ bf16 Bs[128 * 64];   // 16 KB

    const int tid  = threadIdx.x;
    const int lane = tid & 63;
    const int wave = tid >> 6;
    const int quad = lane >> 4;
    const int l16  = lane & 15;

    const int tileM = blockIdx.y * 128;
    const int tileN = blockIdx.x * 128;
    const int wm = (wave >> 1) * 64;
    const int wn = (wave & 1) * 64;

    f32x4 acc[4][4] = {};

    for (int kt = 0; kt < KDIM; kt += 64) {
        #pragma unroll
        for (int i = 0; i < 4; ++i) {
            const int c   = i * 256 + tid;
            const int row = c >> 3;
            const int kg  = (c & 7) ^ (row & 7);   // XOR swizzle
            async_copy16(A + (size_t)(tileM + row) * KDIM + kt + kg * 8,
                         (char*)As + c * 16);
            async_copy16(B + (size_t)(tileN + row) * KDIM + kt + kg * 8,
                         (char*)Bs + c * 16);
        }
        __syncthreads();

        #pragma unroll
        for (int ks = 0; ks < 2; ++ks) {
            const int kq = ks * 4 + quad;
            const int so = (kq ^ (l16 & 7)) * 8;
            bf16x8 aF[4], bF[4];
            #pragma unroll
            for (int mt = 0; mt < 4; ++mt)
                aF[mt] = *(const bf16x8*)(As + (wm + mt * 16 + l16) * 64 + so);
            #pragma unroll
            for (int nt = 0; nt < 4; ++nt)
                bF[nt] = *(const bf16x8*)(Bs + (wn + nt * 16 + l16) * 64 + so);

            #pragma unroll
            for (int mt = 0; mt < 4; ++mt)
                #pragma unroll
                for (int nt = 0; nt < 4; ++nt)
                    acc[mt][nt] = __builtin_amdgcn_mfma_f32_16x16x32_bf16(
                        aF[mt], bF[nt], acc[mt][nt], 0, 0, 0);
        }
        __syncthreads();
    }

    #pragma unroll
    for (int nt = 0; nt < 4; ++nt) {
        const int scol = tileN + wn + nt * 16;
        const float bv = bias[scol + l16];
        #pragma unroll
        for (int mt = 0; mt < 4; ++mt) {
            #pragma unroll
            for (int r = 0; r < 4; ++r) {
                const int rowg = tileM + wm + mt * 16 + quad * 4 + r;
                const float v = acc[mt][nt][r] + bv;
                C[(size_t)rowg * NMAT + scol + l16] = v;
            }
        }
    }
}

__global__ __launch_bounds__(256)
void gemm_proj(const bf16* __restrict__ A, const bf16* __restrict__ B,
               const float* __restrict__ bias, float* __restrict__ C) {
    gemm_body<1024, float>(A, B, bias, C);
}

// ---- 8 bf16 (as uint4) -> 8 floats
__device__ __forceinline__ void bf8_to_f32(const uint4 u, float* f) {
    union { uint32_t u; float f; } c;
    c.u = u.x << 16;         f[0] = c.f;
    c.u = u.x & 0xffff0000u; f[1] = c.f;
    c.u = u.y << 16;         f[2] = c.f;
    c.u = u.y & 0xffff0000u; f[3] = c.f;
    c.u = u.z << 16;         f[4] = c.f;
    c.u = u.z & 0xffff0000u; f[5] = c.f;
    c.u = u.w << 16;         f[6] = c.f;
    c.u = u.w & 0xffff0000u; f[7] = c.f;
}

// Banded attention v4 over [b,h,s,t,d] qkv: 4 threads/query (16 dims each).
__global__ __launch_bounds__(256)
void attn_banded4(const bf16* __restrict__ qkv, bf16* __restrict__ aout) {
    const int tid = threadIdx.x;
    const int qi  = tid >> 2;          // 0..63
    const int ch  = tid & 3;           // 16-dim chunk
    const int t   = blockIdx.x * 64 + qi;
    const int h   = blockIdx.y;
    const int b   = blockIdx.z;

    const size_t bh3 = (size_t)(b * NHEAD + h) * 3;
    const bf16* qb = qkv + (bh3 + 0) * HSLICE + (size_t)t * HDIM + ch * 16;
    const bf16* kb = qkv + (bh3 + 1) * HSLICE + ch * 16;
    const bf16* vb = qkv + (bh3 + 2) * HSLICE + ch * 16;
    const float scale = 0.125f;        // hd^-0.5

    float q16[16];
    {
        const uint4* qp = (const uint4*)qb;
        uint4 u0 = qp[0], u1 = qp[1];
        bf8_to_f32(u0, q16); bf8_to_f32(u1, q16 + 8);
    }

    float sc[2 * RADIUS + 1];
    #pragma unroll
    for (int j = 0; j < 2 * RADIUS + 1; ++j) {
        const int k = t - RADIUS + j;
        const bool valid = (k >= 0) && (k < SEQ);
        const int kc = valid ? k : t;
        const uint4* kp = (const uint4*)(kb + (size_t)kc * HDIM);
        float kf[16];
        uint4 u0 = kp[0], u1 = kp[1];
        bf8_to_f32(u0, kf); bf8_to_f32(u1, kf + 8);
        float p = 0.f;
        #pragma unroll
        for (int e = 0; e < 16; ++e) p = fmaf(q16[e], kf[e], p);
        p += __shfl_xor(p, 1, 64);     // merge 4 chunks
        p += __shfl_xor(p, 2, 64);
        sc[j] = valid ? p * scale : -1e30f;
    }

    float mx = sc[0];
    #pragma unroll
    for (int j = 1; j < 2 * RADIUS + 1; ++j) mx = fmaxf(mx, sc[j]);
    float sum = 0.f;
    #pragma unroll
    for (int j = 0; j < 2 * RADIUS + 1; ++j) { sc[j] = __expf(sc[j] - mx); sum += sc[j]; }
    const float inv = 1.0f / sum;

    float o16[16];
    #pragma unroll
    for (int e = 0; e < 16; ++e) o16[e] = 0.f;
    #pragma unroll
    for (int j = 0; j < 2 * RADIUS + 1; ++j) {
        const int k = t - RADIUS + j;
        const int kc = (k >= 0 && k < SEQ) ? k : t;   // weight ~0 when clamped
        const uint4* vp = (const uint4*)(vb + (size_t)kc * HDIM);
        float vf[16];
        uint4 u0 = vp[0], u1 = vp[1];
        bf8_to_f32(u0, vf); bf8_to_f32(u1, vf + 8);
        const float w = sc[j];
        #pragma unroll
        for (int e = 0; e < 16; ++e) o16[e] = fmaf(w, vf[e], o16[e]);
    }

    bf16* op = aout + ((size_t)b * SEQ + t) * DIM + h * HDIM + ch * 16;
    #pragma unroll
    for (int c2 = 0; c2 < 2; ++c2) {
        union { u16x8 v; __hip_bfloat16 hh[8]; } o;
        #pragma unroll
        for (int e = 0; e < 8; ++e) o.hh[e] = __float2bfloat16(o16[c2 * 8 + e] * inv);
        ((u16x8*)op)[c2] = o.v;
    }
}

extern "C" void kernel_launch(void* const* d_in, const int* in_sizes, int n_in,
                              void* d_out, int out_size, void* d_ws, size_t ws_size,
                              hipStream_t stream) {
    const float* x      = (const float*)d_in[0];
    const float* w_qkv  = (const float*)d_in[1];
    const float* b_qkv  = (const float*)d_in[2];
    const float* w_proj = (const float*)d_in[3];
    const float* b_proj = (const float*)d_in[4];
    float* out = (float*)d_out;

    bf16* xb     = (bf16*)d_ws;
    bf16* wqkvb  = xb + (size_t)ROWS * DIM;
    bf16* wprojb = wqkvb + (size_t)3072 * 1024;
    bf16* qkvb   = wprojb + (size_t)1024 * 1024;   // [b,h,s,t,d], 48 MiB
    bf16* attnb  = qkvb + (size_t)ROWS * 3072;

    const int n1 = ROWS * DIM / 8, n2 = 3072 * 1024 / 8, n3 = 1024 * 1024 / 8;
    cvt_all<<<(n1 + n2 + n3 + 255) / 256, 256, 0, stream>>>(x, xb, n1, w_qkv, wqkvb, n2,
                                                            w_proj, wprojb, n3);

    // GEMM1: 2-phase 128x192, 1024 blocks (64 Mtiles x 16 Ntiles), 2 blocks/CU
    gemm_qkv_2b<<<dim3(1024), 512, 0, stream>>>(xb, wqkvb, b_qkv, qkvb);

    // attn v4: 4 threads/query, 32 waves/CU
    attn_banded4<<<dim3(SEQ / 64, NHEAD, BATCH), 256, 0, stream>>>(qkvb, attnb);

    // GEMM2: 128x128 tiles, 512 blocks
    gemm_proj<<<dim3(1024 / 128, ROWS / 128), 256, 0, stream>>>(attnb, wprojb, b_proj, out);
}

// Round 6
// 187.138 us; speedup vs baseline: 1.1266x; 1.0245x over previous
//
#include <hip/hip_runtime.h>
#include <hip/hip_bf16.h>
#include <cstdint>
#include <cstddef>
#include <type_traits>

// FocalAttention: B=4 T=2048 D=1024 H=16 hd=64 RADIUS=4 (banded, 9-wide window)
// fp32 in/out. cvt(fp32->bf16) -> gemm_qkv (2-phase 128x192, 2 blocks/CU) ->
// banded attn (4 threads/query) -> gemm_proj (2-phase 128x128, 2 blocks/CU, fp32 out).
// r8 lesson: sched_barrier(0) around every barrier = m141 regression (0.55x).
// r9 lesson: grid must be an exact multiple of resident-block capacity.
// r12 lesson: 1 block/CU 8-phase is intra-block serial; K=1024 can't amortize.
// r13 lesson: 2-phase + counted vmcnt + 2 blocks/CU (cross-block TLP) = 59.8us qkv
//   (862 TF, MfmaUtil 35%) — best verified structure for K=1024 on this chip.
// r14 (this round): port the r13 template to gemm_proj (BM=128 BN=128, 512 thr,
//   LDS 64KB -> 2 blocks/CU, grid 512 = 2 exact rounds, XCD swizzle).
//   Ledger: units A=2,B=2; B(t+1)@P1(t), A(t+2)@P2(t); outstanding@P2-end=6
//   -> vmcnt(2) drains exactly tile t+1; tail vmcnt(0) at t=NT-2.

typedef __hip_bfloat16 bf16;
typedef __attribute__((ext_vector_type(8))) short bf16x8;   // A/B frag: 8 bf16 = 4 VGPRs
typedef __attribute__((ext_vector_type(4))) float f32x4;    // C/D frag
typedef __attribute__((ext_vector_type(8))) unsigned short u16x8;

#define BATCH  4
#define SEQ    2048
#define DIM    1024
#define NHEAD  16
#define HDIM   64
#define RADIUS 4
#define ROWS   (BATCH * SEQ)          // 8192
#define KDIM   1024
#define NT     (KDIM / 64)            // 16 K-tiles
#define HSLICE (SEQ * HDIM)           // elems per (b,h,s) slice

__device__ __forceinline__ void async_copy16(const void* gptr, void* lptr) {
    __builtin_amdgcn_global_load_lds(
        (const __attribute__((address_space(1))) unsigned int*)(uintptr_t)gptr,
        (__attribute__((address_space(3))) unsigned int*)(uint32_t)(uintptr_t)lptr,
        16, 0, 0);
}

// Fused fp32 -> bf16 convert for all three tensors, 8 elems/thread.
__global__ __launch_bounds__(256)
void cvt_all(const float* __restrict__ s1, bf16* __restrict__ d1, int n1,
             const float* __restrict__ s2, bf16* __restrict__ d2, int n2,
             const float* __restrict__ s3, bf16* __restrict__ d3, int n3) {
    int i = blockIdx.x * blockDim.x + threadIdx.x;
    const float* src; bf16* dst;
    if (i < n1)              { src = s1; dst = d1; }
    else if (i < n1 + n2)    { i -= n1; src = s2; dst = d2; }
    else if (i < n1+n2+n3)   { i -= n1 + n2; src = s3; dst = d3; }
    else return;
    const float4 a = ((const float4*)src)[2 * i];
    const float4 b = ((const float4*)src)[2 * i + 1];
    union { u16x8 v; __hip_bfloat16 h[8]; } o;
    o.h[0] = __float2bfloat16(a.x); o.h[1] = __float2bfloat16(a.y);
    o.h[2] = __float2bfloat16(a.z); o.h[3] = __float2bfloat16(a.w);
    o.h[4] = __float2bfloat16(b.x); o.h[5] = __float2bfloat16(b.y);
    o.h[6] = __float2bfloat16(b.z); o.h[7] = __float2bfloat16(b.w);
    ((u16x8*)dst)[i] = o.v;
}

#define BAR()        __builtin_amdgcn_s_barrier()
#define WAIT_LGKM0() asm volatile("s_waitcnt lgkmcnt(0)")

// ---------------------------------------------------------------------------
// gemm_qkv: 2-phase 128x192 tile, 2 blocks/CU (r13, verified 59.8us).
// ---------------------------------------------------------------------------

#define STAGE_A2(buf_, kt_) do {                                                \
    _Pragma("unroll")                                                           \
    for (int i_ = 0; i_ < 2; ++i_) {                                            \
        const int c_   = i_ * 512 + tid;                                        \
        const int row_ = c_ >> 3;                                               \
        const int kg_  = (c_ & 7) ^ (row_ & 7);                                 \
        async_copy16(A + (size_t)(tileM + row_) * KDIM + (kt_) + kg_ * 8,       \
                     (char*)As[buf_] + c_ * 16);                                \
    } } while (0)

#define STAGE_B3(buf_, kt_) do {                                                \
    _Pragma("unroll")                                                           \
    for (int j_ = 0; j_ < 3; ++j_) {                                            \
        const int c_   = j_ * 512 + tid;                                        \
        const int row_ = c_ >> 3;                                               \
        const int kg_  = (c_ & 7) ^ (row_ & 7);                                 \
        async_copy16(B + (size_t)(tileN + row_) * KDIM + (kt_) + kg_ * 8,       \
                     (char*)Bs[buf_] + c_ * 16);                                \
    } } while (0)

#define LDA8() do {                                                             \
    _Pragma("unroll")                                                           \
    for (int ks_ = 0; ks_ < 2; ++ks_)                                           \
    _Pragma("unroll")                                                           \
    for (int mt_ = 0; mt_ < 4; ++mt_)                                           \
        aF[ks_][mt_] = *(const bf16x8*)(as_ +                                   \
            (size_t)(wm * 64 + mt_ * 16 + l16) * 64 +                           \
            ((((ks_ << 2) | quad) ^ hh) << 3));                                 \
} while (0)

#define LDBA() do {                                                             \
    _Pragma("unroll")                                                           \
    for (int ks_ = 0; ks_ < 2; ++ks_)                                           \
    _Pragma("unroll")                                                           \
    for (int nt_ = 0; nt_ < 2; ++nt_)                                           \
        bFA[ks_][nt_] = *(const bf16x8*)(bs_ +                                  \
            (size_t)(wn * 48 + nt_ * 16 + l16) * 64 +                           \
            ((((ks_ << 2) | quad) ^ hh) << 3));                                 \
} while (0)

#define LDBB() do {                                                             \
    _Pragma("unroll")                                                           \
    for (int ks_ = 0; ks_ < 2; ++ks_)                                           \
        bFB[ks_] = *(const bf16x8*)(bs_ +                                       \
            (size_t)(wn * 48 + 32 + l16) * 64 +                                 \
            ((((ks_ << 2) | quad) ^ hh) << 3));                                 \
} while (0)

#define MFMA_N01() do {                                                         \
    _Pragma("unroll")                                                           \
    for (int ks_ = 0; ks_ < 2; ++ks_)                                           \
    _Pragma("unroll")                                                           \
    for (int mt_ = 0; mt_ < 4; ++mt_)                                           \
    _Pragma("unroll")                                                           \
    for (int nt_ = 0; nt_ < 2; ++nt_)                                           \
        acc[mt_][nt_] = __builtin_amdgcn_mfma_f32_16x16x32_bf16(                \
            aF[ks_][mt_], bFA[ks_][nt_], acc[mt_][nt_], 0, 0, 0);               \
} while (0)

#define MFMA_N2() do {                                                          \
    _Pragma("unroll")                                                           \
    for (int ks_ = 0; ks_ < 2; ++ks_)                                           \
    _Pragma("unroll")                                                           \
    for (int mt_ = 0; mt_ < 4; ++mt_)                                           \
        acc[mt_][2] = __builtin_amdgcn_mfma_f32_16x16x32_bf16(                  \
            aF[ks_][mt_], bFB[ks_], acc[mt_][2], 0, 0, 0);                      \
} while (0)

__global__ __launch_bounds__(512, 4)   // 4 waves/SIMD -> 2 blocks/CU
void gemm_qkv_2b(const bf16* __restrict__ A, const bf16* __restrict__ B,
                 const float* __restrict__ bias, bf16* __restrict__ C) {
    __shared__ bf16 As[2][128 * 64];   // 32 KB
    __shared__ bf16 Bs[2][192 * 64];   // 48 KB  (80 KB total -> 2 blocks/CU)

    const int tid  = threadIdx.x;
    const int l16  = tid & 15;
    const int quad = (tid >> 4) & 3;
    const int wave = tid >> 6;          // 0..7
    const int wm   = wave >> 2;         // 0..1  (M split, 64 rows each)
    const int wn   = wave & 3;          // 0..3  (N split, 48 cols each)
    const int hh   = l16 & 7;

    // XCD-aware swizzle: grid = 1024 = 64 Mtiles x 16 Ntiles; 1024 % 8 == 0.
    const int bid = (int)blockIdx.x;
    const int seq = (bid & 7) * 128 + (bid >> 3);
    const int tileM = (seq >> 4) * 128;
    const int tileN = (seq & 15) * 192;

    f32x4  acc[4][3] = {};
    bf16x8 aF[2][4], bFA[2][2], bFB[2];

    // prologue: A(0),B(0),A(1) = 7 units; tile0 = first 5 -> vmcnt(2)
    STAGE_A2(0, 0);  STAGE_B3(0, 0);  STAGE_A2(1, 64);
    asm volatile("s_waitcnt vmcnt(2)" ::: "memory");
    BAR();

    #pragma unroll 1
    for (int t = 0; t < NT; ++t) {
        const int buf = t & 1;
        const bf16* __restrict__ as_ = &As[buf][0];
        const bf16* __restrict__ bs_ = &Bs[buf][0];

        // ---- P1: 12 ds_read_b128; stage B(t+1) (region last read P2(t-1)) ----
        LDA8();
        LDBA();
        if (t + 1 < NT) STAGE_B3(buf ^ 1, (t + 1) * 64);
        asm volatile("s_waitcnt lgkmcnt(8)");   // template hint (12 issued)
        BAR();
        WAIT_LGKM0();
        __builtin_amdgcn_s_setprio(1);
        MFMA_N01();
        __builtin_amdgcn_s_setprio(0);
        BAR();

        // ---- P2: 2 ds_read_b128; stage A(t+2) (A(t) reads done @P1) ----
        LDBB();
        if (t + 2 < NT) STAGE_A2(buf, (t + 2) * 64);
        BAR();
        WAIT_LGKM0();
        __builtin_amdgcn_s_setprio(1);
        MFMA_N2();
        __builtin_amdgcn_s_setprio(0);
        // counted drain: keep A(t+2) in flight; tail drains fully at t=NT-2
        if (t + 2 < NT)         asm volatile("s_waitcnt vmcnt(2)" ::: "memory");
        else if (t + 1 < NT)    asm volatile("s_waitcnt vmcnt(0)" ::: "memory");
        BAR();
    }

    // epilogue: C/D layout col = lane&15, row = quad*4 + reg  [m89/m91-verified]
    float  bvs[3];
    size_t cbase[3];   // h,s,d-dependent part of the scatter address
    #pragma unroll
    for (int an = 0; an < 3; ++an) {
        const int cl = tileN + wn * 48 + an * 16 + l16;
        bvs[an] = bias[cl];
        const int s = cl >> 10;
        const int h = (cl >> 6) & (NHEAD - 1);
        const int d = cl & 63;
        cbase[an] = (size_t)(h * 3 + s) * HSLICE + d;
    }
    #pragma unroll
    for (int mt = 0; mt < 4; ++mt) {
        #pragma unroll
        for (int r = 0; r < 4; ++r) {
            const int rowg = tileM + wm * 64 + mt * 16 + quad * 4 + r;
            const int b  = rowg >> 11;
            const int tt = rowg & (SEQ - 1);
            const size_t rb = (size_t)b * (NHEAD * 3) * HSLICE + (size_t)tt * HDIM;
            #pragma unroll
            for (int an = 0; an < 3; ++an)
                C[rb + cbase[an]] = __float2bfloat16(acc[mt][an][r] + bvs[an]);
        }
    }
}

// ---------------------------------------------------------------------------
// gemm_proj: r13 template at BM=128 BN=128, fp32 row-major out.
// ---------------------------------------------------------------------------

#define STAGE_AP(buf_, kt_) do {                                                \
    _Pragma("unroll")                                                           \
    for (int i_ = 0; i_ < 2; ++i_) {                                            \
        const int c_   = i_ * 512 + tid;                                        \
        const int row_ = c_ >> 3;                                               \
        const int kg_  = (c_ & 7) ^ (row_ & 7);                                 \
        async_copy16(A + (size_t)(tileM + row_) * KDIM + (kt_) + kg_ * 8,       \
                     (char*)Ap[buf_] + c_ * 16);                                \
    } } while (0)

#define STAGE_BP(buf_, kt_) do {                                                \
    _Pragma("unroll")                                                           \
    for (int i_ = 0; i_ < 2; ++i_) {                                            \
        const int c_   = i_ * 512 + tid;                                        \
        const int row_ = c_ >> 3;                                               \
        const int kg_  = (c_ & 7) ^ (row_ & 7);                                 \
        async_copy16(B + (size_t)(tileN + row_) * KDIM + (kt_) + kg_ * 8,       \
                     (char*)Bp[buf_] + c_ * 16);                                \
    } } while (0)

#define LDAP() do {                                                             \
    _Pragma("unroll")                                                           \
    for (int ks_ = 0; ks_ < 2; ++ks_)                                           \
    _Pragma("unroll")                                                           \
    for (int mt_ = 0; mt_ < 4; ++mt_)                                           \
        aF[ks_][mt_] = *(const bf16x8*)(as_ +                                   \
            (size_t)(wm * 64 + mt_ * 16 + l16) * 64 +                           \
            ((((ks_ << 2) | quad) ^ hh) << 3));                                 \
} while (0)

#define LDBP(reg_, nt_) do {                                                    \
    _Pragma("unroll")                                                           \
    for (int ks_ = 0; ks_ < 2; ++ks_)                                           \
        reg_[ks_] = *(const bf16x8*)(bs_ +                                      \
            (size_t)(wn * 32 + (nt_) * 16 + l16) * 64 +                         \
            ((((ks_ << 2) | quad) ^ hh) << 3));                                 \
} while (0)

#define MFMA_P(nt_, reg_) do {                                                  \
    _Pragma("unroll")                                                           \
    for (int ks_ = 0; ks_ < 2; ++ks_)                                           \
    _Pragma("unroll")                                                           \
    for (int mt_ = 0; mt_ < 4; ++mt_)                                           \
        acc[mt_][nt_] = __builtin_amdgcn_mfma_f32_16x16x32_bf16(                \
            aF[ks_][mt_], reg_[ks_], acc[mt_][nt_], 0, 0, 0);                   \
} while (0)

__global__ __launch_bounds__(512, 4)   // 4 waves/SIMD -> 2 blocks/CU
void gemm_proj_2b(const bf16* __restrict__ A, const bf16* __restrict__ B,
                  const float* __restrict__ bias, float* __restrict__ C) {
    __shared__ bf16 Ap[2][128 * 64];   // 32 KB
    __shared__ bf16 Bp[2][128 * 64];   // 32 KB  (64 KB total -> 2 blocks/CU)

    const int tid  = threadIdx.x;
    const int l16  = tid & 15;
    const int quad = (tid >> 4) & 3;
    const int wave = tid >> 6;          // 0..7
    const int wm   = wave >> 2;         // 0..1  (M split, 64 rows each)
    const int wn   = wave & 3;          // 0..3  (N split, 32 cols each)
    const int hh   = l16 & 7;

    // XCD-aware swizzle: grid = 512 = 64 Mtiles x 8 Ntiles; 512 % 8 == 0.
    const int bid = (int)blockIdx.x;
    const int seq = (bid & 7) * 64 + (bid >> 3);
    const int tileM = (seq >> 3) * 128;
    const int tileN = (seq & 7) * 128;

    f32x4  acc[4][2] = {};
    bf16x8 aF[2][4], bF0[2], bF1[2];

    // prologue: A(0),B(0),A(1) = 6 units; tile0 = first 4 -> vmcnt(2)
    STAGE_AP(0, 0);  STAGE_BP(0, 0);  STAGE_AP(1, 64);
    asm volatile("s_waitcnt vmcnt(2)" ::: "memory");
    BAR();

    #pragma unroll 1
    for (int t = 0; t < NT; ++t) {
        const int buf = t & 1;
        const bf16* __restrict__ as_ = &Ap[buf][0];
        const bf16* __restrict__ bs_ = &Bp[buf][0];

        // ---- P1: 10 ds_read_b128; stage B(t+1) (region last read P2(t-1)) ----
        LDAP();
        LDBP(bF0, 0);
        if (t + 1 < NT) STAGE_BP(buf ^ 1, (t + 1) * 64);
        asm volatile("s_waitcnt lgkmcnt(8)");   // hint (10 issued)
        BAR();
        WAIT_LGKM0();
        __builtin_amdgcn_s_setprio(1);
        MFMA_P(0, bF0);
        __builtin_amdgcn_s_setprio(0);
        BAR();

        // ---- P2: 2 ds_read_b128; stage A(t+2) (A(t) reads done @P1) ----
        LDBP(bF1, 1);
        if (t + 2 < NT) STAGE_AP(buf, (t + 2) * 64);
        BAR();
        WAIT_LGKM0();
        __builtin_amdgcn_s_setprio(1);
        MFMA_P(1, bF1);
        __builtin_amdgcn_s_setprio(0);
        // counted drain: keep A(t+2) in flight; tail drains fully at t=NT-2
        if (t + 2 < NT)         asm volatile("s_waitcnt vmcnt(2)" ::: "memory");
        else if (t + 1 < NT)    asm volatile("s_waitcnt vmcnt(0)" ::: "memory");
        BAR();
    }

    // epilogue: fp32 row-major; both nt written temporally adjacent (128B/row WC)
    float bvs[2];
    #pragma unroll
    for (int nt = 0; nt < 2; ++nt) bvs[nt] = bias[tileN + wn * 32 + nt * 16 + l16];
    #pragma unroll
    for (int mt = 0; mt < 4; ++mt) {
        #pragma unroll
        for (int r = 0; r < 4; ++r) {
            const int rowg = tileM + wm * 64 + mt * 16 + quad * 4 + r;
            float* cp = C + (size_t)rowg * DIM + tileN + wn * 32 + l16;
            cp[0]  = acc[mt][0][r] + bvs[0];
            cp[16] = acc[mt][1][r] + bvs[1];
        }
    }
}

// ---- 8 bf16 (as uint4) -> 8 floats
__device__ __forceinline__ void bf8_to_f32(const uint4 u, float* f) {
    union { uint32_t u; float f; } c;
    c.u = u.x << 16;         f[0] = c.f;
    c.u = u.x & 0xffff0000u; f[1] = c.f;
    c.u = u.y << 16;         f[2] = c.f;
    c.u = u.y & 0xffff0000u; f[3] = c.f;
    c.u = u.z << 16;         f[4] = c.f;
    c.u = u.z & 0xffff0000u; f[5] = c.f;
    c.u = u.w << 16;         f[6] = c.f;
    c.u = u.w & 0xffff0000u; f[7] = c.f;
}

// Banded attention v4 over [b,h,s,t,d] qkv: 4 threads/query (16 dims each).
__global__ __launch_bounds__(256)
void attn_banded4(const bf16* __restrict__ qkv, bf16* __restrict__ aout) {
    const int tid = threadIdx.x;
    const int qi  = tid >> 2;          // 0..63
    const int ch  = tid & 3;           // 16-dim chunk
    const int t   = blockIdx.x * 64 + qi;
    const int h   = blockIdx.y;
    const int b   = blockIdx.z;

    const size_t bh3 = (size_t)(b * NHEAD + h) * 3;
    const bf16* qb = qkv + (bh3 + 0) * HSLICE + (size_t)t * HDIM + ch * 16;
    const bf16* kb = qkv + (bh3 + 1) * HSLICE + ch * 16;
    const bf16* vb = qkv + (bh3 + 2) * HSLICE + ch * 16;
    const float scale = 0.125f;        // hd^-0.5

    float q16[16];
    {
        const uint4* qp = (const uint4*)qb;
        uint4 u0 = qp[0], u1 = qp[1];
        bf8_to_f32(u0, q16); bf8_to_f32(u1, q16 + 8);
    }

    float sc[2 * RADIUS + 1];
    #pragma unroll
    for (int j = 0; j < 2 * RADIUS + 1; ++j) {
        const int k = t - RADIUS + j;
        const bool valid = (k >= 0) && (k < SEQ);
        const int kc = valid ? k : t;
        const uint4* kp = (const uint4*)(kb + (size_t)kc * HDIM);
        float kf[16];
        uint4 u0 = kp[0], u1 = kp[1];
        bf8_to_f32(u0, kf); bf8_to_f32(u1, kf + 8);
        float p = 0.f;
        #pragma unroll
        for (int e = 0; e < 16; ++e) p = fmaf(q16[e], kf[e], p);
        p += __shfl_xor(p, 1, 64);     // merge 4 chunks
        p += __shfl_xor(p, 2, 64);
        sc[j] = valid ? p * scale : -1e30f;
    }

    float mx = sc[0];
    #pragma unroll
    for (int j = 1; j < 2 * RADIUS + 1; ++j) mx = fmaxf(mx, sc[j]);
    float sum = 0.f;
    #pragma unroll
    for (int j = 0; j < 2 * RADIUS + 1; ++j) { sc[j] = __expf(sc[j] - mx); sum += sc[j]; }
    const float inv = 1.0f / sum;

    float o16[16];
    #pragma unroll
    for (int e = 0; e < 16; ++e) o16[e] = 0.f;
    #pragma unroll
    for (int j = 0; j < 2 * RADIUS + 1; ++j) {
        const int k = t - RADIUS + j;
        const int kc = (k >= 0 && k < SEQ) ? k : t;   // weight ~0 when clamped
        const uint4* vp = (const uint4*)(vb + (size_t)kc * HDIM);
        float vf[16];
        uint4 u0 = vp[0], u1 = vp[1];
        bf8_to_f32(u0, vf); bf8_to_f32(u1, vf + 8);
        const float w = sc[j];
        #pragma unroll
        for (int e = 0; e < 16; ++e) o16[e] = fmaf(w, vf[e], o16[e]);
    }

    bf16* op = aout + ((size_t)b * SEQ + t) * DIM + h * HDIM + ch * 16;
    #pragma unroll
    for (int c2 = 0; c2 < 2; ++c2) {
        union { u16x8 v; __hip_bfloat16 hh[8]; } o;
        #pragma unroll
        for (int e = 0; e < 8; ++e) o.hh[e] = __float2bfloat16(o16[c2 * 8 + e] * inv);
        ((u16x8*)op)[c2] = o.v;
    }
}

extern "C" void kernel_launch(void* const* d_in, const int* in_sizes, int n_in,
                              void* d_out, int out_size, void* d_ws, size_t ws_size,
                              hipStream_t stream) {
    const float* x      = (const float*)d_in[0];
    const float* w_qkv  = (const float*)d_in[1];
    const float* b_qkv  = (const float*)d_in[2];
    const float* w_proj = (const float*)d_in[3];
    const float* b_proj = (const float*)d_in[4];
    float* out = (float*)d_out;

    bf16* xb     = (bf16*)d_ws;
    bf16* wqkvb  = xb + (size_t)ROWS * DIM;
    bf16* wprojb = wqkvb + (size_t)3072 * 1024;
    bf16* qkvb   = wprojb + (size_t)1024 * 1024;   // [b,h,s,t,d], 48 MiB
    bf16* attnb  = qkvb + (size_t)ROWS * 3072;

    const int n1 = ROWS * DIM / 8, n2 = 3072 * 1024 / 8, n3 = 1024 * 1024 / 8;
    cvt_all<<<(n1 + n2 + n3 + 255) / 256, 256, 0, stream>>>(x, xb, n1, w_qkv, wqkvb, n2,
                                                            w_proj, wprojb, n3);

    // GEMM1: 2-phase 128x192, 1024 blocks (64 Mtiles x 16 Ntiles), 2 blocks/CU
    gemm_qkv_2b<<<dim3(1024), 512, 0, stream>>>(xb, wqkvb, b_qkv, qkvb);

    // attn v4: 4 threads/query, 32 waves/CU
    attn_banded4<<<dim3(SEQ / 64, NHEAD, BATCH), 256, 0, stream>>>(qkvb, attnb);

    // GEMM2: 2-phase 128x128, 512 blocks (64 Mtiles x 8 Ntiles), 2 blocks/CU
    gemm_proj_2b<<<dim3(512), 512, 0, stream>>>(attnb, wprojb, b_proj, out);
}